// Round 1
// baseline (451.884 us; speedup 1.0000x reference)
//
#include <hip/hip_runtime.h>
#include <hip/hip_bf16.h>

typedef short short8 __attribute__((ext_vector_type(8)));
typedef __bf16 bf16x8 __attribute__((ext_vector_type(8)));
typedef float f32x4 __attribute__((ext_vector_type(4)));

#define SEQ_N 4096
#define NKEYS 5120
#define PEG_L 5119

__device__ __forceinline__ float b2f(unsigned short s){
  union{unsigned u; float f;} v; v.u = ((unsigned)s)<<16; return v.f;
}
__device__ __forceinline__ unsigned short f2b(float f){
  unsigned u = __builtin_bit_cast(unsigned, f);
  u += 0x7fffu + ((u>>16)&1u);
  return (unsigned short)(u>>16);
}

// ---------------- weight transpose f32 -> bf16 ----------------
// src: [K][Ncols] f32 ; dst: [Ncols][K] bf16
__global__ void k_transpose_w(const float* __restrict__ src, unsigned short* __restrict__ dst,
                              int K, int Ncols){
  __shared__ float t[32][33];
  int tx = threadIdx.x, ty = threadIdx.y;
  int bx = blockIdx.x, by = blockIdx.y;
  #pragma unroll
  for (int i=0;i<4;i++){
    int r = by*32 + ty + 8*i, c = bx*32 + tx;
    t[ty+8*i][tx] = src[(size_t)r*Ncols + c];
  }
  __syncthreads();
  #pragma unroll
  for (int i=0;i<4;i++){
    int r = bx*32 + ty + 8*i, c = by*32 + tx;
    dst[(size_t)r*K + c] = f2b(t[tx][ty+8*i]);
  }
}

// ---------------- LayerNorm: x f32 [8192][512] -> xn bf16 ----------------
__global__ __launch_bounds__(256) void k_layernorm(const float* __restrict__ x,
    const float* __restrict__ g, const float* __restrict__ bb,
    unsigned short* __restrict__ xn){
  int w = threadIdx.x >> 6, l = threadIdx.x & 63;
  int row = blockIdx.x*4 + w;
  const float* xr = x + (size_t)row*512 + l*8;
  f32x4 a = *(const f32x4*)xr;
  f32x4 c4 = *(const f32x4*)(xr+4);
  float s = a[0]+a[1]+a[2]+a[3]+c4[0]+c4[1]+c4[2]+c4[3];
  #pragma unroll
  for (int d=1; d<64; d<<=1) s += __shfl_xor(s, d);
  float mu = s * (1.0f/512.0f);
  float vs = 0.f;
  #pragma unroll
  for (int i=0;i<4;i++){ float d0=a[i]-mu; vs += d0*d0; }
  #pragma unroll
  for (int i=0;i<4;i++){ float d0=c4[i]-mu; vs += d0*d0; }
  #pragma unroll
  for (int d=1; d<64; d<<=1) vs += __shfl_xor(vs, d);
  float rstd = rsqrtf(vs*(1.0f/512.0f) + 1e-5f);
  const float* gp = g + l*8;
  const float* bp = bb + l*8;
  unsigned short o[8];
  #pragma unroll
  for (int i=0;i<8;i++){
    float xi = (i<4)? a[i] : c4[i-4];
    o[i] = f2b((xi-mu)*rstd*gp[i] + bp[i]);
  }
  *(short8*)(xn + (size_t)row*512 + l*8) = *(short8*)o;
}

// ---------------- mem f32 -> bf16 into kf/vf rows 4096..5119 ----------------
__global__ void k_memcat(const float* __restrict__ mem,
                         unsigned short* __restrict__ kf, unsigned short* __restrict__ vf){
  size_t e0 = ((size_t)blockIdx.x*256 + threadIdx.x)*8;
  f32x4 a = *(const f32x4*)(mem+e0);
  f32x4 c4 = *(const f32x4*)(mem+e0+4);
  unsigned short o[8];
  #pragma unroll
  for (int i=0;i<8;i++) o[i] = f2b((i<4)? a[i] : c4[i-4]);
  int c = (int)(e0 & 511);
  size_t row = e0 >> 9;                  // b*1024 + r
  size_t b = row >> 10, r = row & 1023;
  size_t dst = ((b*NKEYS) + 4096 + r)*512 + c;
  *(short8*)(kf+dst) = *(short8*)o;
  *(short8*)(vf+dst) = *(short8*)o;
}

// ---------------- GEMM: C = A[rows][512] * BT[cols][512]^T ----------------
// EPI 0: QKV routing (cols 0..511->q, 512..1023->kf, 1024..1535->vf), all bf16
// EPI 1: out f32 + bias
template<int EPI>
__global__ __launch_bounds__(256) void k_gemm(const unsigned short* __restrict__ A,
    const unsigned short* __restrict__ BT, const float* __restrict__ bias,
    unsigned short* __restrict__ qb, unsigned short* __restrict__ kf,
    unsigned short* __restrict__ vf, float* __restrict__ outf){
  __shared__ unsigned short Al[64][72];
  __shared__ unsigned short Bl[64][72];
  const int tid = threadIdx.x;
  const int w = tid>>6, l = tid&63, m = l&15, hh = l>>4;
  const int m0 = blockIdx.x*64, n0 = blockIdx.y*64;
  const int srow = tid>>2, scg = tid&3;
  f32x4 acc[4];
  #pragma unroll
  for (int nt=0; nt<4; ++nt) acc[nt] = f32x4{0.f,0.f,0.f,0.f};
  const unsigned short* Ap = A + (size_t)(m0+srow)*512 + scg*8;
  const unsigned short* Bp = BT + (size_t)(n0+srow)*512 + scg*8;
  for (int kt=0; kt<8; ++kt){
    short8 a0 = *(const short8*)(Ap + kt*64);
    short8 a1 = *(const short8*)(Ap + kt*64 + 32);
    short8 b0 = *(const short8*)(Bp + kt*64);
    short8 b1 = *(const short8*)(Bp + kt*64 + 32);
    __syncthreads();
    *(short8*)&Al[srow][scg*8]      = a0;
    *(short8*)&Al[srow][32+scg*8]   = a1;
    *(short8*)&Bl[srow][scg*8]      = b0;
    *(short8*)&Bl[srow][32+scg*8]   = b1;
    __syncthreads();
    #pragma unroll
    for (int ks=0; ks<2; ++ks){
      bf16x8 af = *(const bf16x8*)&Al[w*16+m][ks*32 + hh*8];
      #pragma unroll
      for (int nt=0; nt<4; ++nt){
        bf16x8 bfv = *(const bf16x8*)&Bl[nt*16+m][ks*32 + hh*8];
        acc[nt] = __builtin_amdgcn_mfma_f32_16x16x32_bf16(af, bfv, acc[nt], 0,0,0);
      }
    }
  }
  #pragma unroll
  for (int nt=0; nt<4; ++nt){
    #pragma unroll
    for (int j=0; j<4; ++j){
      int grow = m0 + w*16 + 4*hh + j;
      int gcol = n0 + nt*16 + m;
      float v = acc[nt][j];
      if (EPI==0){
        int b = grow >> 12, n = grow & 4095;
        if (gcol < 512)       qb[(size_t)grow*512 + gcol] = f2b(v);
        else if (gcol < 1024) kf[((size_t)b*NKEYS + n)*512 + (gcol-512)]  = f2b(v);
        else                  vf[((size_t)b*NKEYS + n)*512 + (gcol-1024)] = f2b(v);
      } else {
        outf[(size_t)grow*512 + gcol] = v + bias[gcol];
      }
    }
  }
}

// ---------------- PEG1D on rows 1..5119 (x = in rows 1..5119) ----------------
__global__ __launch_bounds__(256) void k_peg(const unsigned short* __restrict__ in,
    const float* __restrict__ w3, const float* __restrict__ bias,
    unsigned short* __restrict__ out){
  int idx = blockIdx.x*256 + threadIdx.x;       // B*5120*64 threads
  int cg = idx & 63;
  int i  = (idx >> 6) % NKEYS;
  int b  = (idx >> 6) / NKEYS;
  int c0 = cg*8;
  const unsigned short* base = in + (size_t)b*NKEYS*512 + c0;
  unsigned short* op = out + ((size_t)b*NKEYS + i)*512 + c0;
  if (i == 0){ *(short8*)op = *(const short8*)base; return; }
  int j = i - 1;                                 // x coordinate
  float wv0[8], wv1[8], wv2[8], bv[8], acc[8];
  #pragma unroll
  for (int k2=0;k2<8;k2++){
    wv0[k2] = w3[(c0+k2)*3 + 0];
    wv1[k2] = w3[(c0+k2)*3 + 1];
    wv2[k2] = w3[(c0+k2)*3 + 2];
    bv[k2]  = bias[c0+k2];
  }
  short8 xc = *(const short8*)(base + (size_t)i*512);   // X(j) = in row j+1 = i
  #pragma unroll
  for (int k2=0;k2<8;k2++)
    acc[k2] = b2f((unsigned short)xc[k2]) * (1.0f + 2.0f*wv1[k2]) + 2.0f*bv[k2];
  int r = j & 31;
  int jj = j + 16; if (jj >= PEG_L) jj -= PEG_L;
  int r2 = jj & 31;
  if (r > 0){
    short8 xl = *(const short8*)(base + (size_t)j*512);  // row (j-1)+1
    #pragma unroll
    for (int k2=0;k2<8;k2++) acc[k2] += wv0[k2]*b2f((unsigned short)xl[k2]);
  }
  if (r < 31 && j+1 < PEG_L){
    short8 xr = *(const short8*)(base + (size_t)(j+2)*512);
    #pragma unroll
    for (int k2=0;k2<8;k2++) acc[k2] += wv2[k2]*b2f((unsigned short)xr[k2]);
  }
  if (r2 > 0){
    int p = jj - 17; if (p < 0) p += PEG_L;
    short8 xl = *(const short8*)(base + (size_t)(p+1)*512);
    #pragma unroll
    for (int k2=0;k2<8;k2++) acc[k2] += wv0[k2]*b2f((unsigned short)xl[k2]);
  }
  if (r2 < 31 && jj+1 < PEG_L){
    int p = jj - 15; if (p < 0) p += PEG_L;
    short8 xr = *(const short8*)(base + (size_t)(p+1)*512);
    #pragma unroll
    for (int k2=0;k2<8;k2++) acc[k2] += wv2[k2]*b2f((unsigned short)xr[k2]);
  }
  unsigned short o[8];
  #pragma unroll
  for (int k2=0;k2<8;k2++) o[k2] = f2b(acc[k2]);
  *(short8*)op = *(short8*)o;
}

// ---------------- V transpose: vp [B][5120][512] -> vpT [B*H][64][5120] ----------------
__global__ __launch_bounds__(256) void k_vtrans(const unsigned short* __restrict__ vp,
                                                unsigned short* __restrict__ vpT){
  __shared__ unsigned short t[64][72];
  const int bh = blockIdx.y, b = bh>>3, h = bh&7;
  const int k0 = blockIdx.x*64;
  const int tid = threadIdx.x;
  #pragma unroll
  for (int it=0; it<2; ++it){
    int idx = tid + it*256;
    int key = idx>>3, dg = idx&7;
    short8 v = *(const short8*)(vp + ((size_t)b*NKEYS + k0+key)*512 + h*64 + dg*8);
    #pragma unroll
    for (int jj=0;jj<8;++jj) t[dg*8+jj][key] = (unsigned short)v[jj];
  }
  __syncthreads();
  #pragma unroll
  for (int it=0; it<2; ++it){
    int idx = tid + it*256;
    int d = idx>>3, kg = idx&7;
    short8 v = *(const short8*)&t[d][kg*8];
    *(short8*)(vpT + ((size_t)bh*64 + d)*NKEYS + k0 + kg*8) = v;
  }
}

// ---------------- Flash attention ----------------
__global__ __launch_bounds__(256) void k_attn(
    const unsigned short* __restrict__ qb,
    const unsigned short* __restrict__ kp,
    const unsigned short* __restrict__ vpT,
    unsigned short* __restrict__ ob){
  __shared__ unsigned short Kl[64][72];
  __shared__ unsigned short Vl[64][72];   // V^T tile: [d][key]
  __shared__ unsigned short Pl[4][16][72];
  const int tid = threadIdx.x;
  const int w = tid >> 6, l = tid & 63;
  const int m = l & 15, hh = l >> 4;
  const int bh = blockIdx.y, b = bh >> 3, h = bh & 7;
  const int q0 = blockIdx.x * 64 + w * 16;

  const unsigned short* qr = qb + (size_t)(b*SEQ_N + q0 + m)*512 + h*64 + hh*8;
  const bf16x8 qf0 = *(const bf16x8*)qr;
  const bf16x8 qf1 = *(const bf16x8*)(qr + 32);

  f32x4 O[4];
  #pragma unroll
  for (int nt=0; nt<4; ++nt) O[nt] = f32x4{0.f,0.f,0.f,0.f};
  float mrun[4] = {-1e30f,-1e30f,-1e30f,-1e30f};
  float lrun[4] = {0.f,0.f,0.f,0.f};

  const unsigned short* kbase = kp + (size_t)b*NKEYS*512 + h*64;
  const unsigned short* vbase = vpT + (size_t)bh*64*NKEYS;
  const int srow = tid >> 3, sg = tid & 7;

  for (int kt=0; kt<80; ++kt){
    const int k0 = kt*64;
    short8 kv0 = *(const short8*)(kbase + (size_t)(k0 + srow)*512 + sg*8);
    short8 kv1 = *(const short8*)(kbase + (size_t)(k0 + srow + 32)*512 + sg*8);
    short8 vv0 = *(const short8*)(vbase + (size_t)srow*NKEYS + k0 + sg*8);
    short8 vv1 = *(const short8*)(vbase + (size_t)(srow+32)*NKEYS + k0 + sg*8);
    __syncthreads();
    *(short8*)&Kl[srow][sg*8]    = kv0;
    *(short8*)&Kl[srow+32][sg*8] = kv1;
    *(short8*)&Vl[srow][sg*8]    = vv0;
    *(short8*)&Vl[srow+32][sg*8] = vv1;
    __syncthreads();

    f32x4 s[4];
    #pragma unroll
    for (int t=0;t<4;++t) s[t] = f32x4{0.f,0.f,0.f,0.f};
    #pragma unroll
    for (int t=0;t<4;++t){
      bf16x8 kf0 = *(const bf16x8*)&Kl[t*16 + m][hh*8];
      s[t] = __builtin_amdgcn_mfma_f32_16x16x32_bf16(qf0, kf0, s[t], 0,0,0);
      bf16x8 kf1 = *(const bf16x8*)&Kl[t*16 + m][32 + hh*8];
      s[t] = __builtin_amdgcn_mfma_f32_16x16x32_bf16(qf1, kf1, s[t], 0,0,0);
    }

    float al[4];
    #pragma unroll
    for (int j=0;j<4;++j){
      float r0 = fmaxf(fmaxf(s[0][j], s[1][j]), fmaxf(s[2][j], s[3][j])) * 0.125f;
      #pragma unroll
      for (int d=1; d<16; d<<=1) r0 = fmaxf(r0, __shfl_xor(r0, d));
      float mn = fmaxf(mrun[j], r0);
      al[j] = __expf(mrun[j] - mn);
      mrun[j] = mn;
      float sum = 0.f;
      #pragma unroll
      for (int t=0;t<4;++t){
        float p = __expf(s[t][j]*0.125f - mn);
        sum += p;
        Pl[w][4*hh + j][m + 16*t] = f2b(p);
      }
      #pragma unroll
      for (int d=1; d<16; d<<=1) sum += __shfl_xor(sum, d);
      lrun[j] = al[j]*lrun[j] + sum;
    }
    #pragma unroll
    for (int nt=0;nt<4;++nt){
      #pragma unroll
      for (int j=0;j<4;++j) O[nt][j] *= al[j];
    }
    __syncthreads();

    bf16x8 pf0 = *(const bf16x8*)&Pl[w][m][hh*8];
    bf16x8 pf1 = *(const bf16x8*)&Pl[w][m][32 + hh*8];
    #pragma unroll
    for (int nt=0;nt<4;++nt){
      bf16x8 v0 = *(const bf16x8*)&Vl[nt*16 + m][hh*8];
      O[nt] = __builtin_amdgcn_mfma_f32_16x16x32_bf16(pf0, v0, O[nt], 0,0,0);
      bf16x8 v1 = *(const bf16x8*)&Vl[nt*16 + m][32 + hh*8];
      O[nt] = __builtin_amdgcn_mfma_f32_16x16x32_bf16(pf1, v1, O[nt], 0,0,0);
    }
  }

  #pragma unroll
  for (int j=0;j<4;++j){
    const float inv = 1.0f / lrun[j];
    unsigned short* orow = ob + (size_t)(b*SEQ_N + q0 + 4*hh + j)*512 + h*64;
    #pragma unroll
    for (int nt=0;nt<4;++nt) orow[nt*16 + m] = f2b(O[nt][j]*inv);
  }
}

extern "C" void kernel_launch(void* const* d_in, const int* in_sizes, int n_in,
                              void* d_out, int out_size, void* d_ws, size_t ws_size,
                              hipStream_t stream){
  const float* x     = (const float*)d_in[0];
  const float* mem   = (const float*)d_in[1];
  const float* ln_g  = (const float*)d_in[2];
  const float* ln_b  = (const float*)d_in[3];
  const float* w_qkv = (const float*)d_in[4];
  const float* w_out = (const float*)d_in[5];
  const float* b_out = (const float*)d_in[6];
  const float* pk_w  = (const float*)d_in[7];
  const float* pk_b  = (const float*)d_in[8];
  const float* pv_w  = (const float*)d_in[9];
  const float* pv_b  = (const float*)d_in[10];
  float* outp = (float*)d_out;

  char* ws = (char*)d_ws;
  size_t off = 0;
  auto alloc = [&](size_t bytes)->void*{
    void* p = ws + off; off += (bytes + 255) & ~(size_t)255; return p;
  };
  unsigned short* wqkvT = (unsigned short*)alloc((size_t)1536*512*2);
  unsigned short* woutT = (unsigned short*)alloc((size_t)512*512*2);
  unsigned short* xn    = (unsigned short*)alloc((size_t)8192*512*2);
  unsigned short* q_b   = (unsigned short*)alloc((size_t)8192*512*2);
  unsigned short* kf    = (unsigned short*)alloc((size_t)2*NKEYS*512*2);
  unsigned short* vf    = (unsigned short*)alloc((size_t)2*NKEYS*512*2);
  unsigned short* kpg   = (unsigned short*)alloc((size_t)2*NKEYS*512*2);
  unsigned short* vpg   = (unsigned short*)alloc((size_t)2*NKEYS*512*2);
  unsigned short* vpT   = (unsigned short*)alloc((size_t)2*NKEYS*512*2);
  unsigned short* attnb = (unsigned short*)alloc((size_t)8192*512*2);

  k_transpose_w<<<dim3(48,16), dim3(32,8), 0, stream>>>(w_qkv, wqkvT, 512, 1536);
  k_transpose_w<<<dim3(16,16), dim3(32,8), 0, stream>>>(w_out, woutT, 512, 512);
  k_layernorm<<<2048, 256, 0, stream>>>(x, ln_g, ln_b, xn);
  k_memcat<<<512, 256, 0, stream>>>(mem, kf, vf);
  k_gemm<0><<<dim3(128,24), 256, 0, stream>>>(xn, wqkvT, nullptr, q_b, kf, vf, nullptr);
  k_peg<<<2560, 256, 0, stream>>>(kf, pk_w, pk_b, kpg);
  k_peg<<<2560, 256, 0, stream>>>(vf, pv_w, pv_b, vpg);
  k_vtrans<<<dim3(80,16), 256, 0, stream>>>(vpg, vpT);
  k_attn<<<dim3(64,16), 256, 0, stream>>>(q_b, kpg, vpT, attnb);
  k_gemm<1><<<dim3(128,8), 256, 0, stream>>>(attnb, woutT, b_out, nullptr, nullptr, nullptr, outp);
}

// Round 4
// 345.256 us; speedup vs baseline: 1.3088x; 1.3088x over previous
//
#include <hip/hip_runtime.h>
#include <hip/hip_bf16.h>

typedef short short8 __attribute__((ext_vector_type(8)));
typedef __bf16 bf16x8 __attribute__((ext_vector_type(8)));
typedef float f32x4 __attribute__((ext_vector_type(4)));
typedef float f32x16 __attribute__((ext_vector_type(16)));
typedef unsigned int uint4v __attribute__((ext_vector_type(4)));

#define SEQ_N 4096
#define NKEYS 5120
#define PEG_L 5119

__device__ __forceinline__ float b2f(unsigned short s){
  union{unsigned u; float f;} v; v.u = ((unsigned)s)<<16; return v.f;
}
__device__ __forceinline__ unsigned short f2b(float f){
  unsigned u = __builtin_bit_cast(unsigned, f);
  u += 0x7fffu + ((u>>16)&1u);
  return (unsigned short)(u>>16);
}
// pack 2 floats -> bf16x2 word (lo -> [15:0], hi -> [31:16]), RNE
__device__ __forceinline__ unsigned pkbf(float lo, float hi){
  return ((unsigned)f2b(hi) << 16) | (unsigned)f2b(lo);
}

// ---------------- weight transpose f32 -> bf16 ----------------
__global__ void k_transpose_w(const float* __restrict__ src, unsigned short* __restrict__ dst,
                              int K, int Ncols){
  __shared__ float t[32][33];
  int tx = threadIdx.x, ty = threadIdx.y;
  int bx = blockIdx.x, by = blockIdx.y;
  #pragma unroll
  for (int i=0;i<4;i++){
    int r = by*32 + ty + 8*i, c = bx*32 + tx;
    t[ty+8*i][tx] = src[(size_t)r*Ncols + c];
  }
  __syncthreads();
  #pragma unroll
  for (int i=0;i<4;i++){
    int r = bx*32 + ty + 8*i, c = by*32 + tx;
    dst[(size_t)r*K + c] = f2b(t[tx][ty+8*i]);
  }
}

// ---------------- LayerNorm: x f32 [8192][512] -> xn bf16 ----------------
__global__ __launch_bounds__(256) void k_layernorm(const float* __restrict__ x,
    const float* __restrict__ g, const float* __restrict__ bb,
    unsigned short* __restrict__ xn){
  int w = threadIdx.x >> 6, l = threadIdx.x & 63;
  int row = blockIdx.x*4 + w;
  const float* xr = x + (size_t)row*512 + l*8;
  f32x4 a = *(const f32x4*)xr;
  f32x4 c4 = *(const f32x4*)(xr+4);
  float s = a[0]+a[1]+a[2]+a[3]+c4[0]+c4[1]+c4[2]+c4[3];
  #pragma unroll
  for (int d=1; d<64; d<<=1) s += __shfl_xor(s, d);
  float mu = s * (1.0f/512.0f);
  float vs = 0.f;
  #pragma unroll
  for (int i=0;i<4;i++){ float d0=a[i]-mu; vs += d0*d0; }
  #pragma unroll
  for (int i=0;i<4;i++){ float d0=c4[i]-mu; vs += d0*d0; }
  #pragma unroll
  for (int d=1; d<64; d<<=1) vs += __shfl_xor(vs, d);
  float rstd = rsqrtf(vs*(1.0f/512.0f) + 1e-5f);
  const float* gp = g + l*8;
  const float* bp = bb + l*8;
  unsigned short o[8];
  #pragma unroll
  for (int i=0;i<8;i++){
    float xi = (i<4)? a[i] : c4[i-4];
    o[i] = f2b((xi-mu)*rstd*gp[i] + bp[i]);
  }
  *(short8*)(xn + (size_t)row*512 + l*8) = *(short8*)o;
}

// ---------------- mem f32 -> bf16 into kf/vf rows 4096..5119 ----------------
__global__ void k_memcat(const float* __restrict__ mem,
                         unsigned short* __restrict__ kf, unsigned short* __restrict__ vf){
  size_t e0 = ((size_t)blockIdx.x*256 + threadIdx.x)*8;
  f32x4 a = *(const f32x4*)(mem+e0);
  f32x4 c4 = *(const f32x4*)(mem+e0+4);
  unsigned short o[8];
  #pragma unroll
  for (int i=0;i<8;i++) o[i] = f2b((i<4)? a[i] : c4[i-4]);
  int c = (int)(e0 & 511);
  size_t row = e0 >> 9;
  size_t b = row >> 10, r = row & 1023;
  size_t dst = ((b*NKEYS) + 4096 + r)*512 + c;
  *(short8*)(kf+dst) = *(short8*)o;
  *(short8*)(vf+dst) = *(short8*)o;
}

// ---------------- GEMM: C = A[rows][512] * BT[cols][512]^T ----------------
template<int EPI>
__global__ __launch_bounds__(256) void k_gemm(const unsigned short* __restrict__ A,
    const unsigned short* __restrict__ BT, const float* __restrict__ bias,
    unsigned short* __restrict__ qb, unsigned short* __restrict__ kf,
    unsigned short* __restrict__ vf, float* __restrict__ outf){
  __shared__ unsigned short Al[64][72];
  __shared__ unsigned short Bl[64][72];
  const int tid = threadIdx.x;
  const int w = tid>>6, l = tid&63, m = l&15, hh = l>>4;
  const int m0 = blockIdx.x*64, n0 = blockIdx.y*64;
  const int srow = tid>>2, scg = tid&3;
  f32x4 acc[4];
  #pragma unroll
  for (int nt=0; nt<4; ++nt) acc[nt] = f32x4{0.f,0.f,0.f,0.f};
  const unsigned short* Ap = A + (size_t)(m0+srow)*512 + scg*8;
  const unsigned short* Bp = BT + (size_t)(n0+srow)*512 + scg*8;
  for (int kt=0; kt<8; ++kt){
    short8 a0 = *(const short8*)(Ap + kt*64);
    short8 a1 = *(const short8*)(Ap + kt*64 + 32);
    short8 b0 = *(const short8*)(Bp + kt*64);
    short8 b1 = *(const short8*)(Bp + kt*64 + 32);
    __syncthreads();
    *(short8*)&Al[srow][scg*8]      = a0;
    *(short8*)&Al[srow][32+scg*8]   = a1;
    *(short8*)&Bl[srow][scg*8]      = b0;
    *(short8*)&Bl[srow][32+scg*8]   = b1;
    __syncthreads();
    #pragma unroll
    for (int ks=0; ks<2; ++ks){
      bf16x8 af = *(const bf16x8*)&Al[w*16+m][ks*32 + hh*8];
      #pragma unroll
      for (int nt=0; nt<4; ++nt){
        bf16x8 bfv = *(const bf16x8*)&Bl[nt*16+m][ks*32 + hh*8];
        acc[nt] = __builtin_amdgcn_mfma_f32_16x16x32_bf16(af, bfv, acc[nt], 0,0,0);
      }
    }
  }
  #pragma unroll
  for (int nt=0; nt<4; ++nt){
    #pragma unroll
    for (int j=0; j<4; ++j){
      int grow = m0 + w*16 + 4*hh + j;
      int gcol = n0 + nt*16 + m;
      float v = acc[nt][j];
      if (EPI==0){
        int b = grow >> 12, n = grow & 4095;
        if (gcol < 512)       qb[(size_t)grow*512 + gcol] = f2b(v);
        else if (gcol < 1024) kf[((size_t)b*NKEYS + n)*512 + (gcol-512)]  = f2b(v);
        else                  vf[((size_t)b*NKEYS + n)*512 + (gcol-1024)] = f2b(v);
      } else {
        outf[(size_t)grow*512 + gcol] = v + bias[gcol];
      }
    }
  }
}

// ---------------- PEG1D on rows 1..5119 ----------------
__global__ __launch_bounds__(256) void k_peg(const unsigned short* __restrict__ in,
    const float* __restrict__ w3, const float* __restrict__ bias,
    unsigned short* __restrict__ out){
  int idx = blockIdx.x*256 + threadIdx.x;
  int cg = idx & 63;
  int i  = (idx >> 6) % NKEYS;
  int b  = (idx >> 6) / NKEYS;
  int c0 = cg*8;
  const unsigned short* base = in + (size_t)b*NKEYS*512 + c0;
  unsigned short* op = out + ((size_t)b*NKEYS + i)*512 + c0;
  if (i == 0){ *(short8*)op = *(const short8*)base; return; }
  int j = i - 1;
  float wv0[8], wv1[8], wv2[8], bv[8], acc[8];
  #pragma unroll
  for (int k2=0;k2<8;k2++){
    wv0[k2] = w3[(c0+k2)*3 + 0];
    wv1[k2] = w3[(c0+k2)*3 + 1];
    wv2[k2] = w3[(c0+k2)*3 + 2];
    bv[k2]  = bias[c0+k2];
  }
  short8 xc = *(const short8*)(base + (size_t)i*512);
  #pragma unroll
  for (int k2=0;k2<8;k2++)
    acc[k2] = b2f((unsigned short)xc[k2]) * (1.0f + 2.0f*wv1[k2]) + 2.0f*bv[k2];
  int r = j & 31;
  int jj = j + 16; if (jj >= PEG_L) jj -= PEG_L;
  int r2 = jj & 31;
  if (r > 0){
    short8 xl = *(const short8*)(base + (size_t)j*512);
    #pragma unroll
    for (int k2=0;k2<8;k2++) acc[k2] += wv0[k2]*b2f((unsigned short)xl[k2]);
  }
  if (r < 31 && j+1 < PEG_L){
    short8 xr = *(const short8*)(base + (size_t)(j+2)*512);
    #pragma unroll
    for (int k2=0;k2<8;k2++) acc[k2] += wv2[k2]*b2f((unsigned short)xr[k2]);
  }
  if (r2 > 0){
    int p = jj - 17; if (p < 0) p += PEG_L;
    short8 xl = *(const short8*)(base + (size_t)(p+1)*512);
    #pragma unroll
    for (int k2=0;k2<8;k2++) acc[k2] += wv0[k2]*b2f((unsigned short)xl[k2]);
  }
  if (r2 < 31 && jj+1 < PEG_L){
    int p = jj - 15; if (p < 0) p += PEG_L;
    short8 xr = *(const short8*)(base + (size_t)(p+1)*512);
    #pragma unroll
    for (int k2=0;k2<8;k2++) acc[k2] += wv2[k2]*b2f((unsigned short)xr[k2]);
  }
  unsigned short o[8];
  #pragma unroll
  for (int k2=0;k2<8;k2++) o[k2] = f2b(acc[k2]);
  *(short8*)op = *(short8*)o;
}

// ---------------- V transpose: vp [B][5120][512] -> vpT [B*H][64][5120] ----------------
__global__ __launch_bounds__(256) void k_vtrans(const unsigned short* __restrict__ vp,
                                                unsigned short* __restrict__ vpT){
  __shared__ unsigned short t[64][72];
  const int bh = blockIdx.y, b = bh>>3, h = bh&7;
  const int k0 = blockIdx.x*64;
  const int tid = threadIdx.x;
  #pragma unroll
  for (int it=0; it<2; ++it){
    int idx = tid + it*256;
    int key = idx>>3, dg = idx&7;
    short8 v = *(const short8*)(vp + ((size_t)b*NKEYS + k0+key)*512 + h*64 + dg*8);
    #pragma unroll
    for (int jj=0;jj<8;++jj) t[dg*8+jj][key] = (unsigned short)v[jj];
  }
  __syncthreads();
  #pragma unroll
  for (int it=0; it<2; ++it){
    int idx = tid + it*256;
    int d = idx>>3, kg = idx&7;
    short8 v = *(const short8*)&t[d][kg*8];
    *(short8*)(vpT + ((size_t)bh*64 + d)*NKEYS + k0 + kg*8) = v;
  }
}

// ---------------- Flash attention: swapped QK^T, 32x32, in-register softmax ----------------
// 4 waves x 32 queries = 128 q/block. Double-buffered K/V LDS, T14 async staging.
// All cross-half exchanges via __shfl_xor(.,32) (semantics-safe); bf16 packs via f2b (RNE).
__global__ __launch_bounds__(256) void k_attn(
    const unsigned short* __restrict__ qb,
    const unsigned short* __restrict__ kp,
    const unsigned short* __restrict__ vpT,
    unsigned short* __restrict__ ob){
  __shared__ unsigned short Kl[2][64][72];
  __shared__ unsigned short Vl[2][64][72];
  const int tid = threadIdx.x;
  const int w = tid >> 6, lid = tid & 63;
  const int lq = lid & 31, hi = lid >> 5;
  const int bh = blockIdx.y, b = bh >> 3, h = bh & 7;
  const int q = blockIdx.x*128 + w*32 + lq;

  // Q fragments (B-operand of swapped QK^T): Q[q][dt*16 + hi*8 .. +8]
  bf16x8 qreg[4];
  {
    const unsigned short* qr = qb + (size_t)(b*SEQ_N + q)*512 + h*64 + hi*8;
    #pragma unroll
    for (int dt=0; dt<4; ++dt) qreg[dt] = *(const bf16x8*)(qr + dt*16);
  }

  f32x16 o0 = {}, o1 = {};
  float mraw = -3.0e38f, lsum = 0.f;

  const int srow = tid >> 2, sg = tid & 3;
  const unsigned short* kst = kp + (size_t)b*NKEYS*512 + h*64 + (size_t)srow*512 + sg*8;
  const unsigned short* vst = vpT + (size_t)bh*64*NKEYS + (size_t)srow*NKEYS + sg*8;

  // prologue: stage tile 0 into buf 0
  {
    short8 a0 = *(const short8*)(kst);
    short8 a1 = *(const short8*)(kst + 32);
    short8 v0 = *(const short8*)(vst);
    short8 v1 = *(const short8*)(vst + 32);
    *(short8*)&Kl[0][srow][sg*8]    = a0;
    *(short8*)&Kl[0][srow][32+sg*8] = a1;
    *(short8*)&Vl[0][srow][sg*8]    = v0;
    *(short8*)&Vl[0][srow][32+sg*8] = v1;
  }
  __syncthreads();

  const float c2 = 0.18033688011f;   // 0.125 * log2(e)
  int cur = 0;
  for (int kt=0; kt<80; ++kt){
    // T14: issue next tile's global loads before compute
    short8 a0, a1, v0s, v1s;
    const bool pf = (kt+1) < 80;
    if (pf){
      const unsigned short* kn = kst + (size_t)(kt+1)*64*512;
      const unsigned short* vn = vst + (size_t)(kt+1)*64;
      a0  = *(const short8*)(kn);
      a1  = *(const short8*)(kn + 32);
      v0s = *(const short8*)(vn);
      v1s = *(const short8*)(vn + 32);
    }

    // QK^T swapped: S^T[key][q], 2 subtiles of 32 keys
    f32x16 s0 = {}, s1 = {};
    #pragma unroll
    for (int dt=0; dt<4; ++dt){
      bf16x8 kf0 = *(const bf16x8*)&Kl[cur][lq][dt*16 + hi*8];
      s0 = __builtin_amdgcn_mfma_f32_32x32x16_bf16(kf0, qreg[dt], s0, 0,0,0);
    }
    #pragma unroll
    for (int dt=0; dt<4; ++dt){
      bf16x8 kf1 = *(const bf16x8*)&Kl[cur][32+lq][dt*16 + hi*8];
      s1 = __builtin_amdgcn_mfma_f32_32x32x16_bf16(kf1, qreg[dt], s1, 0,0,0);
    }

    // row max: in-register tree + cross-half shfl
    float t8[8];
    #pragma unroll
    for (int i=0;i<8;++i) t8[i] = fmaxf(fmaxf(s0[i], s0[i+8]), fmaxf(s1[i], s1[i+8]));
    #pragma unroll
    for (int i=0;i<4;++i) t8[i] = fmaxf(t8[i], t8[i+4]);
    float pm = fmaxf(fmaxf(t8[0],t8[1]), fmaxf(t8[2],t8[3]));
    pm = fmaxf(pm, __shfl_xor(pm, 32, 64));

    // T13 defer-max: raw threshold 64 = 8 in exp domain
    if (!__all(pm <= mraw + 64.0f)){
      float mnew = fmaxf(mraw, pm);
      float al = exp2f((mraw - mnew)*c2);
      #pragma unroll
      for (int i=0;i<16;++i){ o0[i]*=al; o1[i]*=al; }
      lsum *= al;
      mraw = mnew;
    }
    const float mc = mraw * c2;
    #pragma unroll
    for (int i=0;i<16;++i){
      s0[i] = exp2f(fmaf(s0[i], c2, -mc));
      s1[i] = exp2f(fmaf(s1[i], c2, -mc));
    }
    // sum
    float u8[8];
    #pragma unroll
    for (int i=0;i<8;++i) u8[i] = (s0[i]+s0[i+8]) + (s1[i]+s1[i+8]);
    #pragma unroll
    for (int i=0;i<4;++i) u8[i] += u8[i+4];
    float ps = (u8[0]+u8[1]) + (u8[2]+u8[3]);
    ps += __shfl_xor(ps, 32, 64);
    lsum += ps;

    // P -> bf16 B-fragments: pack pairs, one cross-half exchange per slice
    float p[32];
    #pragma unroll
    for (int i=0;i<16;++i){ p[i] = s0[i]; p[16+i] = s1[i]; }
    #pragma unroll
    for (int sl=0; sl<4; ++sl){
      const int rb = sl*8;
      // lane(hi=h) holds keys (sl*16) + {4h+0,4h+1,4h+2,4h+3, 8+4h+0..3} in p[rb..rb+7]
      unsigned w0 = pkbf(p[rb+0], p[rb+1]);   // keys 4h+0,1
      unsigned w1 = pkbf(p[rb+2], p[rb+3]);   // keys 4h+2,3
      unsigned w2 = pkbf(p[rb+4], p[rb+5]);   // keys 8+4h+0,1
      unsigned w3 = pkbf(p[rb+6], p[rb+7]);   // keys 8+4h+2,3
      // B-fragment: low lanes need keys 0..7 = [w0,w1, partner w0, partner w1]
      //             high lanes need keys 8..15 = [partner w2, partner w3, w2, w3]
      unsigned u0 = hi ? w0 : w2;
      unsigned u1 = hi ? w1 : w3;
      unsigned su0 = __shfl_xor(u0, 32, 64);
      unsigned su1 = __shfl_xor(u1, 32, 64);
      unsigned e0 = hi ? su0 : w0;
      unsigned e1 = hi ? su1 : w1;
      unsigned e2 = hi ? w2 : su0;
      unsigned e3 = hi ? w3 : su1;
      uint4v wv = {e0, e1, e2, e3};
      bf16x8 pb = __builtin_bit_cast(bf16x8, wv);
      bf16x8 vf0 = *(const bf16x8*)&Vl[cur][lq][sl*16 + hi*8];
      o0 = __builtin_amdgcn_mfma_f32_32x32x16_bf16(vf0, pb, o0, 0,0,0);
      bf16x8 vf1 = *(const bf16x8*)&Vl[cur][32+lq][sl*16 + hi*8];
      o1 = __builtin_amdgcn_mfma_f32_32x32x16_bf16(vf1, pb, o1, 0,0,0);
    }

    // write prefetched tile into other buffer, one barrier per tile
    if (pf){
      *(short8*)&Kl[cur^1][srow][sg*8]    = a0;
      *(short8*)&Kl[cur^1][srow][32+sg*8] = a1;
      *(short8*)&Vl[cur^1][srow][sg*8]    = v0s;
      *(short8*)&Vl[cur^1][srow][32+sg*8] = v1s;
    }
    __syncthreads();
    cur ^= 1;
  }

  const float inv = 1.0f / lsum;
  unsigned short* obase = ob + (size_t)(b*SEQ_N + q)*512 + h*64;
  #pragma unroll
  for (int r=0; r<16; r+=2){
    const int dloc = (r&3) + 8*(r>>2) + 4*hi;
    *(unsigned*)(obase + dloc)      = pkbf(o0[r]*inv, o0[r+1]*inv);
    *(unsigned*)(obase + 32 + dloc) = pkbf(o1[r]*inv, o1[r+1]*inv);
  }
}

extern "C" void kernel_launch(void* const* d_in, const int* in_sizes, int n_in,
                              void* d_out, int out_size, void* d_ws, size_t ws_size,
                              hipStream_t stream){
  const float* x     = (const float*)d_in[0];
  const float* mem   = (const float*)d_in[1];
  const float* ln_g  = (const float*)d_in[2];
  const float* ln_b  = (const float*)d_in[3];
  const float* w_qkv = (const float*)d_in[4];
  const float* w_out = (const float*)d_in[5];
  const float* b_out = (const float*)d_in[6];
  const float* pk_w  = (const float*)d_in[7];
  const float* pk_b  = (const float*)d_in[8];
  const float* pv_w  = (const float*)d_in[9];
  const float* pv_b  = (const float*)d_in[10];
  float* outp = (float*)d_out;

  char* ws = (char*)d_ws;
  size_t off = 0;
  auto alloc = [&](size_t bytes)->void*{
    void* p = ws + off; off += (bytes + 255) & ~(size_t)255; return p;
  };
  unsigned short* wqkvT = (unsigned short*)alloc((size_t)1536*512*2);
  unsigned short* woutT = (unsigned short*)alloc((size_t)512*512*2);
  unsigned short* xn    = (unsigned short*)alloc((size_t)8192*512*2);
  unsigned short* q_b   = (unsigned short*)alloc((size_t)8192*512*2);
  unsigned short* kf    = (unsigned short*)alloc((size_t)2*NKEYS*512*2);
  unsigned short* vf    = (unsigned short*)alloc((size_t)2*NKEYS*512*2);
  unsigned short* kpg   = (unsigned short*)alloc((size_t)2*NKEYS*512*2);
  unsigned short* vpg   = (unsigned short*)alloc((size_t)2*NKEYS*512*2);
  unsigned short* vpT   = (unsigned short*)alloc((size_t)2*NKEYS*512*2);
  unsigned short* attnb = (unsigned short*)alloc((size_t)8192*512*2);

  k_transpose_w<<<dim3(48,16), dim3(32,8), 0, stream>>>(w_qkv, wqkvT, 512, 1536);
  k_transpose_w<<<dim3(16,16), dim3(32,8), 0, stream>>>(w_out, woutT, 512, 512);
  k_layernorm<<<2048, 256, 0, stream>>>(x, ln_g, ln_b, xn);
  k_memcat<<<512, 256, 0, stream>>>(mem, kf, vf);
  k_gemm<0><<<dim3(128,24), 256, 0, stream>>>(xn, wqkvT, nullptr, q_b, kf, vf, nullptr);
  k_peg<<<2560, 256, 0, stream>>>(kf, pk_w, pk_b, kpg);
  k_peg<<<2560, 256, 0, stream>>>(vf, pv_w, pv_b, vpg);
  k_vtrans<<<dim3(80,16), 256, 0, stream>>>(vpg, vpT);
  k_attn<<<dim3(32,16), 256, 0, stream>>>(q_b, kpg, vpT, attnb);
  k_gemm<1><<<dim3(128,8), 256, 0, stream>>>(attnb, woutT, b_out, nullptr, nullptr, nullptr, outp);
}

// Round 5
// 312.672 us; speedup vs baseline: 1.4452x; 1.1042x over previous
//
#include <hip/hip_runtime.h>
#include <hip/hip_bf16.h>

typedef short short8 __attribute__((ext_vector_type(8)));
typedef __bf16 bf16x8 __attribute__((ext_vector_type(8)));
typedef float f32x4 __attribute__((ext_vector_type(4)));
typedef float f32x8 __attribute__((ext_vector_type(8)));
typedef float f32x16 __attribute__((ext_vector_type(16)));
typedef unsigned int uint4v __attribute__((ext_vector_type(4)));

#define SEQ_N 4096
#define NKEYS 5120
#define PEG_L 5119
#define NSPLIT 2
#define KEYS_PER_SPLIT 2560
#define NT_SPLIT 40

__device__ __forceinline__ float b2f(unsigned short s){
  union{unsigned u; float f;} v; v.u = ((unsigned)s)<<16; return v.f;
}
__device__ __forceinline__ unsigned short f2b(float f){
  unsigned u = __builtin_bit_cast(unsigned, f);
  u += 0x7fffu + ((u>>16)&1u);
  return (unsigned short)(u>>16);
}
// HW packed f32->bf16x2 (D[15:0]=bf16(lo), D[31:16]=bf16(hi))
__device__ __forceinline__ unsigned cvtpk(float lo, float hi){
  unsigned r;
  asm("v_cvt_pk_bf16_f32 %0, %1, %2" : "=v"(r) : "v"(lo), "v"(hi));
  return r;
}

// ---------------- weight transpose f32 -> bf16 ----------------
__global__ void k_transpose_w(const float* __restrict__ src, unsigned short* __restrict__ dst,
                              int K, int Ncols){
  __shared__ float t[32][33];
  int tx = threadIdx.x, ty = threadIdx.y;
  int bx = blockIdx.x, by = blockIdx.y;
  #pragma unroll
  for (int i=0;i<4;i++){
    int r = by*32 + ty + 8*i, c = bx*32 + tx;
    t[ty+8*i][tx] = src[(size_t)r*Ncols + c];
  }
  __syncthreads();
  #pragma unroll
  for (int i=0;i<4;i++){
    int r = bx*32 + ty + 8*i, c = by*32 + tx;
    dst[(size_t)r*K + c] = f2b(t[tx][ty+8*i]);
  }
}

// ---------------- LayerNorm: x f32 [8192][512] -> xn bf16 ----------------
__global__ __launch_bounds__(256) void k_layernorm(const float* __restrict__ x,
    const float* __restrict__ g, const float* __restrict__ bb,
    unsigned short* __restrict__ xn){
  int w = threadIdx.x >> 6, l = threadIdx.x & 63;
  int row = blockIdx.x*4 + w;
  const float* xr = x + (size_t)row*512 + l*8;
  f32x4 a = *(const f32x4*)xr;
  f32x4 c4 = *(const f32x4*)(xr+4);
  float s = a[0]+a[1]+a[2]+a[3]+c4[0]+c4[1]+c4[2]+c4[3];
  #pragma unroll
  for (int d=1; d<64; d<<=1) s += __shfl_xor(s, d);
  float mu = s * (1.0f/512.0f);
  float vs = 0.f;
  #pragma unroll
  for (int i=0;i<4;i++){ float d0=a[i]-mu; vs += d0*d0; }
  #pragma unroll
  for (int i=0;i<4;i++){ float d0=c4[i]-mu; vs += d0*d0; }
  #pragma unroll
  for (int d=1; d<64; d<<=1) vs += __shfl_xor(vs, d);
  float rstd = rsqrtf(vs*(1.0f/512.0f) + 1e-5f);
  const float* gp = g + l*8;
  const float* bp = bb + l*8;
  unsigned short o[8];
  #pragma unroll
  for (int i=0;i<8;i++){
    float xi = (i<4)? a[i] : c4[i-4];
    o[i] = f2b((xi-mu)*rstd*gp[i] + bp[i]);
  }
  *(short8*)(xn + (size_t)row*512 + l*8) = *(short8*)o;
}

// ---------------- mem f32 -> bf16 into kf/vf rows 4096..5119 ----------------
__global__ void k_memcat(const float* __restrict__ mem,
                         unsigned short* __restrict__ kf, unsigned short* __restrict__ vf){
  size_t e0 = ((size_t)blockIdx.x*256 + threadIdx.x)*8;
  f32x4 a = *(const f32x4*)(mem+e0);
  f32x4 c4 = *(const f32x4*)(mem+e0+4);
  unsigned short o[8];
  #pragma unroll
  for (int i=0;i<8;i++) o[i] = f2b((i<4)? a[i] : c4[i-4]);
  int c = (int)(e0 & 511);
  size_t row = e0 >> 9;
  size_t b = row >> 10, r = row & 1023;
  size_t dst = ((b*NKEYS) + 4096 + r)*512 + c;
  *(short8*)(kf+dst) = *(short8*)o;
  *(short8*)(vf+dst) = *(short8*)o;
}

// ---------------- GEMM: C = A[rows][512] * BT[cols][512]^T ----------------
template<int EPI>
__global__ __launch_bounds__(256) void k_gemm(const unsigned short* __restrict__ A,
    const unsigned short* __restrict__ BT, const float* __restrict__ bias,
    unsigned short* __restrict__ qb, unsigned short* __restrict__ kf,
    unsigned short* __restrict__ vf, float* __restrict__ outf){
  __shared__ unsigned short Al[64][72];
  __shared__ unsigned short Bl[64][72];
  const int tid = threadIdx.x;
  const int w = tid>>6, l = tid&63, m = l&15, hh = l>>4;
  const int m0 = blockIdx.x*64, n0 = blockIdx.y*64;
  const int srow = tid>>2, scg = tid&3;
  f32x4 acc[4];
  #pragma unroll
  for (int nt=0; nt<4; ++nt) acc[nt] = f32x4{0.f,0.f,0.f,0.f};
  const unsigned short* Ap = A + (size_t)(m0+srow)*512 + scg*8;
  const unsigned short* Bp = BT + (size_t)(n0+srow)*512 + scg*8;
  for (int kt=0; kt<8; ++kt){
    short8 a0 = *(const short8*)(Ap + kt*64);
    short8 a1 = *(const short8*)(Ap + kt*64 + 32);
    short8 b0 = *(const short8*)(Bp + kt*64);
    short8 b1 = *(const short8*)(Bp + kt*64 + 32);
    __syncthreads();
    *(short8*)&Al[srow][scg*8]      = a0;
    *(short8*)&Al[srow][32+scg*8]   = a1;
    *(short8*)&Bl[srow][scg*8]      = b0;
    *(short8*)&Bl[srow][32+scg*8]   = b1;
    __syncthreads();
    #pragma unroll
    for (int ks=0; ks<2; ++ks){
      bf16x8 af = *(const bf16x8*)&Al[w*16+m][ks*32 + hh*8];
      #pragma unroll
      for (int nt=0; nt<4; ++nt){
        bf16x8 bfv = *(const bf16x8*)&Bl[nt*16+m][ks*32 + hh*8];
        acc[nt] = __builtin_amdgcn_mfma_f32_16x16x32_bf16(af, bfv, acc[nt], 0,0,0);
      }
    }
  }
  #pragma unroll
  for (int nt=0; nt<4; ++nt){
    #pragma unroll
    for (int j=0; j<4; ++j){
      int grow = m0 + w*16 + 4*hh + j;
      int gcol = n0 + nt*16 + m;
      float v = acc[nt][j];
      if (EPI==0){
        int b = grow >> 12, n = grow & 4095;
        if (gcol < 512)       qb[(size_t)grow*512 + gcol] = f2b(v);
        else if (gcol < 1024) kf[((size_t)b*NKEYS + n)*512 + (gcol-512)]  = f2b(v);
        else                  vf[((size_t)b*NKEYS + n)*512 + (gcol-1024)] = f2b(v);
      } else {
        outf[(size_t)grow*512 + gcol] = v + bias[gcol];
      }
    }
  }
}

// ---------------- PEG1D on rows 1..5119 ----------------
__global__ __launch_bounds__(256) void k_peg(const unsigned short* __restrict__ in,
    const float* __restrict__ w3, const float* __restrict__ bias,
    unsigned short* __restrict__ out){
  int idx = blockIdx.x*256 + threadIdx.x;
  int cg = idx & 63;
  int i  = (idx >> 6) % NKEYS;
  int b  = (idx >> 6) / NKEYS;
  int c0 = cg*8;
  const unsigned short* base = in + (size_t)b*NKEYS*512 + c0;
  unsigned short* op = out + ((size_t)b*NKEYS + i)*512 + c0;
  if (i == 0){ *(short8*)op = *(const short8*)base; return; }
  int j = i - 1;
  float wv0[8], wv1[8], wv2[8], bv[8], acc[8];
  #pragma unroll
  for (int k2=0;k2<8;k2++){
    wv0[k2] = w3[(c0+k2)*3 + 0];
    wv1[k2] = w3[(c0+k2)*3 + 1];
    wv2[k2] = w3[(c0+k2)*3 + 2];
    bv[k2]  = bias[c0+k2];
  }
  short8 xc = *(const short8*)(base + (size_t)i*512);
  #pragma unroll
  for (int k2=0;k2<8;k2++)
    acc[k2] = b2f((unsigned short)xc[k2]) * (1.0f + 2.0f*wv1[k2]) + 2.0f*bv[k2];
  int r = j & 31;
  int jj = j + 16; if (jj >= PEG_L) jj -= PEG_L;
  int r2 = jj & 31;
  if (r > 0){
    short8 xl = *(const short8*)(base + (size_t)j*512);
    #pragma unroll
    for (int k2=0;k2<8;k2++) acc[k2] += wv0[k2]*b2f((unsigned short)xl[k2]);
  }
  if (r < 31 && j+1 < PEG_L){
    short8 xr = *(const short8*)(base + (size_t)(j+2)*512);
    #pragma unroll
    for (int k2=0;k2<8;k2++) acc[k2] += wv2[k2]*b2f((unsigned short)xr[k2]);
  }
  if (r2 > 0){
    int p = jj - 17; if (p < 0) p += PEG_L;
    short8 xl = *(const short8*)(base + (size_t)(p+1)*512);
    #pragma unroll
    for (int k2=0;k2<8;k2++) acc[k2] += wv0[k2]*b2f((unsigned short)xl[k2]);
  }
  if (r2 < 31 && jj+1 < PEG_L){
    int p = jj - 15; if (p < 0) p += PEG_L;
    short8 xr = *(const short8*)(base + (size_t)(p+1)*512);
    #pragma unroll
    for (int k2=0;k2<8;k2++) acc[k2] += wv2[k2]*b2f((unsigned short)xr[k2]);
  }
  unsigned short o[8];
  #pragma unroll
  for (int k2=0;k2<8;k2++) o[k2] = f2b(acc[k2]);
  *(short8*)op = *(short8*)o;
}

// ---------------- V transpose: vp [B][5120][512] -> vpT [B*H][64][5120] ----------------
__global__ __launch_bounds__(256) void k_vtrans(const unsigned short* __restrict__ vp,
                                                unsigned short* __restrict__ vpT){
  __shared__ unsigned short t[64][72];
  const int bh = blockIdx.y, b = bh>>3, h = bh&7;
  const int k0 = blockIdx.x*64;
  const int tid = threadIdx.x;
  #pragma unroll
  for (int it=0; it<2; ++it){
    int idx = tid + it*256;
    int key = idx>>3, dg = idx&7;
    short8 v = *(const short8*)(vp + ((size_t)b*NKEYS + k0+key)*512 + h*64 + dg*8);
    #pragma unroll
    for (int jj=0;jj<8;++jj) t[dg*8+jj][key] = (unsigned short)v[jj];
  }
  __syncthreads();
  #pragma unroll
  for (int it=0; it<2; ++it){
    int idx = tid + it*256;
    int d = idx>>3, kg = idx&7;
    short8 v = *(const short8*)&t[d][kg*8];
    *(short8*)(vpT + ((size_t)bh*64 + d)*NKEYS + k0 + kg*8) = v;
  }
}

// ---------------- Flash attention (key-split): swapped QK^T, 32x32, in-reg softmax ----------------
// grid (32, 16, NSPLIT); 4 waves x 32 q = 128 q/block; each split covers 2560 keys (40 tiles).
// Outputs per-split normalized partial O (bf16) + (m_raw, l) for the combine pass.
__global__ __launch_bounds__(256, 4) void k_attn(
    const unsigned short* __restrict__ qb,
    const unsigned short* __restrict__ kp,
    const unsigned short* __restrict__ vpT,
    unsigned short* __restrict__ oP,
    float* __restrict__ ml){
  __shared__ unsigned short Kl[2][64][72];
  __shared__ unsigned short Vl[2][64][72];
  const int tid = threadIdx.x;
  const int w = tid >> 6, lid = tid & 63;
  const int lq = lid & 31, hi = lid >> 5;
  const int bh = blockIdx.y, b = bh >> 3, h = bh & 7;
  const int sp = blockIdx.z;
  const int q = blockIdx.x*128 + w*32 + lq;

  bf16x8 qreg[4];
  {
    const unsigned short* qr = qb + (size_t)(b*SEQ_N + q)*512 + h*64 + hi*8;
    #pragma unroll
    for (int dt=0; dt<4; ++dt) qreg[dt] = *(const bf16x8*)(qr + dt*16);
  }

  f32x16 o0 = {}, o1 = {};
  float mraw = -3.0e38f, lsum = 0.f;   // lsum = this half's partial

  const int srow = tid >> 2, sg = tid & 3;
  const unsigned short* kst = kp + (size_t)b*NKEYS*512 + h*64
                              + (size_t)(sp*KEYS_PER_SPLIT)*512 + (size_t)srow*512 + sg*8;
  const unsigned short* vst = vpT + (size_t)bh*64*NKEYS + (size_t)srow*NKEYS
                              + sp*KEYS_PER_SPLIT + sg*8;

  {
    short8 a0 = *(const short8*)(kst);
    short8 a1 = *(const short8*)(kst + 32);
    short8 v0 = *(const short8*)(vst);
    short8 v1 = *(const short8*)(vst + 32);
    *(short8*)&Kl[0][srow][sg*8]    = a0;
    *(short8*)&Kl[0][srow][32+sg*8] = a1;
    *(short8*)&Vl[0][srow][sg*8]    = v0;
    *(short8*)&Vl[0][srow][32+sg*8] = v1;
  }
  __syncthreads();

  const float c2 = 0.18033688011f;   // 0.125 * log2(e)
  int cur = 0;
  for (int kt=0; kt<NT_SPLIT; ++kt){
    short8 a0, a1, v0s, v1s;
    const bool pf = (kt+1) < NT_SPLIT;
    if (pf){
      const unsigned short* kn = kst + (size_t)(kt+1)*64*512;
      const unsigned short* vn = vst + (size_t)(kt+1)*64;
      a0  = *(const short8*)(kn);
      a1  = *(const short8*)(kn + 32);
      v0s = *(const short8*)(vn);
      v1s = *(const short8*)(vn + 32);
    }

    f32x16 s0 = {}, s1 = {};
    #pragma unroll
    for (int dt=0; dt<4; ++dt){
      bf16x8 kf0 = *(const bf16x8*)&Kl[cur][lq][dt*16 + hi*8];
      s0 = __builtin_amdgcn_mfma_f32_32x32x16_bf16(kf0, qreg[dt], s0, 0,0,0);
    }
    #pragma unroll
    for (int dt=0; dt<4; ++dt){
      bf16x8 kf1 = *(const bf16x8*)&Kl[cur][32+lq][dt*16 + hi*8];
      s1 = __builtin_amdgcn_mfma_f32_32x32x16_bf16(kf1, qreg[dt], s1, 0,0,0);
    }

    // local (this half's) max via packed tree
    f32x8 sa0 = __builtin_shufflevector(s0, s0, 0,1,2,3,4,5,6,7);
    f32x8 sb0 = __builtin_shufflevector(s0, s0, 8,9,10,11,12,13,14,15);
    f32x8 sa1 = __builtin_shufflevector(s1, s1, 0,1,2,3,4,5,6,7);
    f32x8 sb1 = __builtin_shufflevector(s1, s1, 8,9,10,11,12,13,14,15);
    f32x8 mx8 = __builtin_elementwise_max(__builtin_elementwise_max(sa0, sb0),
                                          __builtin_elementwise_max(sa1, sb1));
    float pm = fmaxf(fmaxf(fmaxf(mx8[0],mx8[1]), fmaxf(mx8[2],mx8[3])),
                     fmaxf(fmaxf(mx8[4],mx8[5]), fmaxf(mx8[6],mx8[7])));

    // defer-max: cross-half exchange + rescale only when some lane exceeds slack
    if (!__all(pm <= mraw + 64.0f)){
      float pg = fmaxf(pm, __shfl_xor(pm, 32, 64));
      float mnew = fmaxf(mraw, pg);
      float al = exp2f((mraw - mnew)*c2);
      #pragma unroll
      for (int i=0;i<16;++i){ o0[i]*=al; o1[i]*=al; }
      lsum *= al;
      mraw = mnew;
    }
    const float nmc = -(mraw * c2);
    #pragma unroll
    for (int i=0;i<16;++i){
      s0[i] = exp2f(fmaf(s0[i], c2, nmc));
      s1[i] = exp2f(fmaf(s1[i], c2, nmc));
    }
    // partial sum (this half only; cross-half combine deferred to epilogue)
    {
      f32x8 pa0 = __builtin_shufflevector(s0, s0, 0,1,2,3,4,5,6,7);
      f32x8 pb0 = __builtin_shufflevector(s0, s0, 8,9,10,11,12,13,14,15);
      f32x8 pa1 = __builtin_shufflevector(s1, s1, 0,1,2,3,4,5,6,7);
      f32x8 pb1 = __builtin_shufflevector(s1, s1, 8,9,10,11,12,13,14,15);
      f32x8 u = (pa0 + pb0) + (pa1 + pb1);
      f32x4 u4 = f32x4{u[0],u[1],u[2],u[3]} + f32x4{u[4],u[5],u[6],u[7]};
      lsum += (u4[0]+u4[1]) + (u4[2]+u4[3]);
    }

    // P -> bf16 B-fragments (HW cvt_pk), one cross-half exchange per 16-key slice
    #pragma unroll
    for (int sl=0; sl<4; ++sl){
      const f32x16& sv = (sl < 2) ? s0 : s1;
      const int rb = (sl & 1)*8;
      unsigned w0 = cvtpk(sv[rb+0], sv[rb+1]);
      unsigned w1 = cvtpk(sv[rb+2], sv[rb+3]);
      unsigned w2 = cvtpk(sv[rb+4], sv[rb+5]);
      unsigned w3 = cvtpk(sv[rb+6], sv[rb+7]);
      unsigned u0 = hi ? w0 : w2;
      unsigned u1 = hi ? w1 : w3;
      unsigned su0 = __shfl_xor(u0, 32, 64);
      unsigned su1 = __shfl_xor(u1, 32, 64);
      unsigned e0 = hi ? su0 : w0;
      unsigned e1 = hi ? su1 : w1;
      unsigned e2 = hi ? w2 : su0;
      unsigned e3 = hi ? w3 : su1;
      uint4v wv = {e0, e1, e2, e3};
      bf16x8 pb = __builtin_bit_cast(bf16x8, wv);
      bf16x8 vf0 = *(const bf16x8*)&Vl[cur][lq][sl*16 + hi*8];
      o0 = __builtin_amdgcn_mfma_f32_32x32x16_bf16(vf0, pb, o0, 0,0,0);
      bf16x8 vf1 = *(const bf16x8*)&Vl[cur][32+lq][sl*16 + hi*8];
      o1 = __builtin_amdgcn_mfma_f32_32x32x16_bf16(vf1, pb, o1, 0,0,0);
    }

    if (pf){
      *(short8*)&Kl[cur^1][srow][sg*8]    = a0;
      *(short8*)&Kl[cur^1][srow][32+sg*8] = a1;
      *(short8*)&Vl[cur^1][srow][sg*8]    = v0s;
      *(short8*)&Vl[cur^1][srow][32+sg*8] = v1s;
    }
    __syncthreads();
    cur ^= 1;
  }

  const float lt = lsum + __shfl_xor(lsum, 32, 64);
  const float inv = 1.0f / lt;
  unsigned short* op = oP + (((size_t)(sp*16 + bh)*SEQ_N + q)*64);
  #pragma unroll
  for (int r=0; r<16; r+=2){
    const int dloc = (r&3) + 8*(r>>2) + 4*hi;
    *(unsigned*)(op + dloc)      = cvtpk(o0[r]*inv, o0[r+1]*inv);
    *(unsigned*)(op + 32 + dloc) = cvtpk(o1[r]*inv, o1[r+1]*inv);
  }
  float* mlp = ml + ((size_t)(sp*16 + bh)*SEQ_N + q)*2;
  mlp[0] = mraw;
  mlp[1] = lt;
}

// ---------------- combine two key-splits ----------------
__global__ __launch_bounds__(256) void k_combine(const unsigned short* __restrict__ oP,
    const float* __restrict__ ml, unsigned short* __restrict__ attnb){
  const float c2 = 0.18033688011f;
  int idx = blockIdx.x*256 + threadIdx.x;     // 4096*16*8 threads
  int dg = idx & 7;
  int qbh = idx >> 3;
  int q = qbh & 4095;
  int bh = qbh >> 12;
  int b = bh >> 3, h = bh & 7;
  size_t i0 = ((size_t)bh*SEQ_N + q);
  size_t i1 = ((size_t)(16 + bh)*SEQ_N + q);
  short8 a = *(const short8*)(oP + i0*64 + dg*8);
  short8 c = *(const short8*)(oP + i1*64 + dg*8);
  float m0 = ml[i0*2], l0 = ml[i0*2+1];
  float m1 = ml[i1*2], l1 = ml[i1*2+1];
  float ms = fmaxf(m0, m1);
  float w0 = l0 * exp2f((m0 - ms)*c2);
  float w1 = l1 * exp2f((m1 - ms)*c2);
  float inv = 1.0f / (w0 + w1);
  float a0 = w0*inv, a1 = w1*inv;
  unsigned short o[8];
  #pragma unroll
  for (int k2=0;k2<8;k2++)
    o[k2] = f2b(a0*b2f((unsigned short)a[k2]) + a1*b2f((unsigned short)c[k2]));
  *(short8*)(attnb + ((size_t)(b*SEQ_N + q)*512) + h*64 + dg*8) = *(short8*)o;
}

extern "C" void kernel_launch(void* const* d_in, const int* in_sizes, int n_in,
                              void* d_out, int out_size, void* d_ws, size_t ws_size,
                              hipStream_t stream){
  const float* x     = (const float*)d_in[0];
  const float* mem   = (const float*)d_in[1];
  const float* ln_g  = (const float*)d_in[2];
  const float* ln_b  = (const float*)d_in[3];
  const float* w_qkv = (const float*)d_in[4];
  const float* w_out = (const float*)d_in[5];
  const float* b_out = (const float*)d_in[6];
  const float* pk_w  = (const float*)d_in[7];
  const float* pk_b  = (const float*)d_in[8];
  const float* pv_w  = (const float*)d_in[9];
  const float* pv_b  = (const float*)d_in[10];
  float* outp = (float*)d_out;

  char* ws = (char*)d_ws;
  size_t off = 0;
  auto alloc = [&](size_t bytes)->void*{
    void* p = ws + off; off += (bytes + 255) & ~(size_t)255; return p;
  };
  unsigned short* wqkvT = (unsigned short*)alloc((size_t)1536*512*2);
  unsigned short* woutT = (unsigned short*)alloc((size_t)512*512*2);
  unsigned short* xn    = (unsigned short*)alloc((size_t)8192*512*2);
  unsigned short* q_b   = (unsigned short*)alloc((size_t)8192*512*2);
  unsigned short* kf    = (unsigned short*)alloc((size_t)2*NKEYS*512*2);
  unsigned short* vf    = (unsigned short*)alloc((size_t)2*NKEYS*512*2);
  unsigned short* kpg   = (unsigned short*)alloc((size_t)2*NKEYS*512*2);
  unsigned short* vpg   = (unsigned short*)alloc((size_t)2*NKEYS*512*2);
  unsigned short* vpT   = (unsigned short*)alloc((size_t)2*NKEYS*512*2);
  unsigned short* attnb = (unsigned short*)alloc((size_t)8192*512*2);

  // Split-attention partials overlay the dead kf/vf region (kf,vf are adjacent):
  // oP: 2 splits x 16 bh x 4096 q x 64 d bf16 = 16.78 MB; ml: 2x16x4096x2 f32 = 1.05 MB.
  unsigned short* oP = kf;
  float* ml = (float*)((char*)kf + (size_t)NSPLIT*16*SEQ_N*64*2);

  k_transpose_w<<<dim3(48,16), dim3(32,8), 0, stream>>>(w_qkv, wqkvT, 512, 1536);
  k_transpose_w<<<dim3(16,16), dim3(32,8), 0, stream>>>(w_out, woutT, 512, 512);
  k_layernorm<<<2048, 256, 0, stream>>>(x, ln_g, ln_b, xn);
  k_memcat<<<512, 256, 0, stream>>>(mem, kf, vf);
  k_gemm<0><<<dim3(128,24), 256, 0, stream>>>(xn, wqkvT, nullptr, q_b, kf, vf, nullptr);
  k_peg<<<2560, 256, 0, stream>>>(kf, pk_w, pk_b, kpg);
  k_peg<<<2560, 256, 0, stream>>>(vf, pv_w, pv_b, vpg);
  k_vtrans<<<dim3(80,16), 256, 0, stream>>>(vpg, vpT);
  k_attn<<<dim3(32,16,NSPLIT), 256, 0, stream>>>(q_b, kpg, vpT, oP, ml);
  k_combine<<<2048, 256, 0, stream>>>(oP, ml, attnb);
  k_gemm<1><<<dim3(128,8), 256, 0, stream>>>(attnb, woutT, b_out, nullptr, nullptr, nullptr, outp);
}

// Round 6
// 311.109 us; speedup vs baseline: 1.4525x; 1.0050x over previous
//
#include <hip/hip_runtime.h>
#include <hip/hip_bf16.h>

typedef short short8 __attribute__((ext_vector_type(8)));
typedef __bf16 bf16x8 __attribute__((ext_vector_type(8)));
typedef float f32x4 __attribute__((ext_vector_type(4)));
typedef float f32x8 __attribute__((ext_vector_type(8)));
typedef float f32x16 __attribute__((ext_vector_type(16)));
typedef unsigned int uint4v __attribute__((ext_vector_type(4)));

#define SEQ_N 4096
#define NKEYS 5120
#define PEG_L 5119
#define NSPLIT 2
#define KEYS_PER_SPLIT 2560
#define NT_SPLIT 40

__device__ __forceinline__ float b2f(unsigned short s){
  union{unsigned u; float f;} v; v.u = ((unsigned)s)<<16; return v.f;
}
__device__ __forceinline__ unsigned short f2b(float f){
  unsigned u = __builtin_bit_cast(unsigned, f);
  u += 0x7fffu + ((u>>16)&1u);
  return (unsigned short)(u>>16);
}
// HW packed f32->bf16x2 (D[15:0]=bf16(lo), D[31:16]=bf16(hi))
__device__ __forceinline__ unsigned cvtpk(float lo, float hi){
  unsigned r;
  asm("v_cvt_pk_bf16_f32 %0, %1, %2" : "=v"(r) : "v"(lo), "v"(hi));
  return r;
}

// ---------------- weight transpose f32 -> bf16 ----------------
__global__ void k_transpose_w(const float* __restrict__ src, unsigned short* __restrict__ dst,
                              int K, int Ncols){
  __shared__ float t[32][33];
  int tx = threadIdx.x, ty = threadIdx.y;
  int bx = blockIdx.x, by = blockIdx.y;
  #pragma unroll
  for (int i=0;i<4;i++){
    int r = by*32 + ty + 8*i, c = bx*32 + tx;
    t[ty+8*i][tx] = src[(size_t)r*Ncols + c];
  }
  __syncthreads();
  #pragma unroll
  for (int i=0;i<4;i++){
    int r = bx*32 + ty + 8*i, c = by*32 + tx;
    dst[(size_t)r*K + c] = f2b(t[tx][ty+8*i]);
  }
}

// ---------------- LayerNorm: x f32 [8192][512] -> xn bf16 ----------------
__global__ __launch_bounds__(256) void k_layernorm(const float* __restrict__ x,
    const float* __restrict__ g, const float* __restrict__ bb,
    unsigned short* __restrict__ xn){
  int w = threadIdx.x >> 6, l = threadIdx.x & 63;
  int row = blockIdx.x*4 + w;
  const float* xr = x + (size_t)row*512 + l*8;
  f32x4 a = *(const f32x4*)xr;
  f32x4 c4 = *(const f32x4*)(xr+4);
  float s = a[0]+a[1]+a[2]+a[3]+c4[0]+c4[1]+c4[2]+c4[3];
  #pragma unroll
  for (int d=1; d<64; d<<=1) s += __shfl_xor(s, d);
  float mu = s * (1.0f/512.0f);
  float vs = 0.f;
  #pragma unroll
  for (int i=0;i<4;i++){ float d0=a[i]-mu; vs += d0*d0; }
  #pragma unroll
  for (int i=0;i<4;i++){ float d0=c4[i]-mu; vs += d0*d0; }
  #pragma unroll
  for (int d=1; d<64; d<<=1) vs += __shfl_xor(vs, d);
  float rstd = rsqrtf(vs*(1.0f/512.0f) + 1e-5f);
  const float* gp = g + l*8;
  const float* bp = bb + l*8;
  unsigned short o[8];
  #pragma unroll
  for (int i=0;i<8;i++){
    float xi = (i<4)? a[i] : c4[i-4];
    o[i] = f2b((xi-mu)*rstd*gp[i] + bp[i]);
  }
  *(short8*)(xn + (size_t)row*512 + l*8) = *(short8*)o;
}

// ---------------- mem f32 -> bf16 into kf/vf rows 4096..5119 ----------------
__global__ void k_memcat(const float* __restrict__ mem,
                         unsigned short* __restrict__ kf, unsigned short* __restrict__ vf){
  size_t e0 = ((size_t)blockIdx.x*256 + threadIdx.x)*8;
  f32x4 a = *(const f32x4*)(mem+e0);
  f32x4 c4 = *(const f32x4*)(mem+e0+4);
  unsigned short o[8];
  #pragma unroll
  for (int i=0;i<8;i++) o[i] = f2b((i<4)? a[i] : c4[i-4]);
  int c = (int)(e0 & 511);
  size_t row = e0 >> 9;
  size_t b = row >> 10, r = row & 1023;
  size_t dst = ((b*NKEYS) + 4096 + r)*512 + c;
  *(short8*)(kf+dst) = *(short8*)o;
  *(short8*)(vf+dst) = *(short8*)o;
}

// ---------------- GEMM: C = A[rows][512] * BT[cols][512]^T ----------------
template<int EPI>
__global__ __launch_bounds__(256) void k_gemm(const unsigned short* __restrict__ A,
    const unsigned short* __restrict__ BT, const float* __restrict__ bias,
    unsigned short* __restrict__ qb, unsigned short* __restrict__ kf,
    unsigned short* __restrict__ vf, float* __restrict__ outf){
  __shared__ unsigned short Al[64][72];
  __shared__ unsigned short Bl[64][72];
  const int tid = threadIdx.x;
  const int w = tid>>6, l = tid&63, m = l&15, hh = l>>4;
  const int m0 = blockIdx.x*64, n0 = blockIdx.y*64;
  const int srow = tid>>2, scg = tid&3;
  f32x4 acc[4];
  #pragma unroll
  for (int nt=0; nt<4; ++nt) acc[nt] = f32x4{0.f,0.f,0.f,0.f};
  const unsigned short* Ap = A + (size_t)(m0+srow)*512 + scg*8;
  const unsigned short* Bp = BT + (size_t)(n0+srow)*512 + scg*8;
  for (int kt=0; kt<8; ++kt){
    short8 a0 = *(const short8*)(Ap + kt*64);
    short8 a1 = *(const short8*)(Ap + kt*64 + 32);
    short8 b0 = *(const short8*)(Bp + kt*64);
    short8 b1 = *(const short8*)(Bp + kt*64 + 32);
    __syncthreads();
    *(short8*)&Al[srow][scg*8]      = a0;
    *(short8*)&Al[srow][32+scg*8]   = a1;
    *(short8*)&Bl[srow][scg*8]      = b0;
    *(short8*)&Bl[srow][32+scg*8]   = b1;
    __syncthreads();
    #pragma unroll
    for (int ks=0; ks<2; ++ks){
      bf16x8 af = *(const bf16x8*)&Al[w*16+m][ks*32 + hh*8];
      #pragma unroll
      for (int nt=0; nt<4; ++nt){
        bf16x8 bfv = *(const bf16x8*)&Bl[nt*16+m][ks*32 + hh*8];
        acc[nt] = __builtin_amdgcn_mfma_f32_16x16x32_bf16(af, bfv, acc[nt], 0,0,0);
      }
    }
  }
  #pragma unroll
  for (int nt=0; nt<4; ++nt){
    #pragma unroll
    for (int j=0; j<4; ++j){
      int grow = m0 + w*16 + 4*hh + j;
      int gcol = n0 + nt*16 + m;
      float v = acc[nt][j];
      if (EPI==0){
        int b = grow >> 12, n = grow & 4095;
        if (gcol < 512)       qb[(size_t)grow*512 + gcol] = f2b(v);
        else if (gcol < 1024) kf[((size_t)b*NKEYS + n)*512 + (gcol-512)]  = f2b(v);
        else                  vf[((size_t)b*NKEYS + n)*512 + (gcol-1024)] = f2b(v);
      } else {
        outf[(size_t)grow*512 + gcol] = v + bias[gcol];
      }
    }
  }
}

// ---------------- PEG1D on rows 1..5119 ----------------
__global__ __launch_bounds__(256) void k_peg(const unsigned short* __restrict__ in,
    const float* __restrict__ w3, const float* __restrict__ bias,
    unsigned short* __restrict__ out){
  int idx = blockIdx.x*256 + threadIdx.x;
  int cg = idx & 63;
  int i  = (idx >> 6) % NKEYS;
  int b  = (idx >> 6) / NKEYS;
  int c0 = cg*8;
  const unsigned short* base = in + (size_t)b*NKEYS*512 + c0;
  unsigned short* op = out + ((size_t)b*NKEYS + i)*512 + c0;
  if (i == 0){ *(short8*)op = *(const short8*)base; return; }
  int j = i - 1;
  float wv0[8], wv1[8], wv2[8], bv[8], acc[8];
  #pragma unroll
  for (int k2=0;k2<8;k2++){
    wv0[k2] = w3[(c0+k2)*3 + 0];
    wv1[k2] = w3[(c0+k2)*3 + 1];
    wv2[k2] = w3[(c0+k2)*3 + 2];
    bv[k2]  = bias[c0+k2];
  }
  short8 xc = *(const short8*)(base + (size_t)i*512);
  #pragma unroll
  for (int k2=0;k2<8;k2++)
    acc[k2] = b2f((unsigned short)xc[k2]) * (1.0f + 2.0f*wv1[k2]) + 2.0f*bv[k2];
  int r = j & 31;
  int jj = j + 16; if (jj >= PEG_L) jj -= PEG_L;
  int r2 = jj & 31;
  if (r > 0){
    short8 xl = *(const short8*)(base + (size_t)j*512);
    #pragma unroll
    for (int k2=0;k2<8;k2++) acc[k2] += wv0[k2]*b2f((unsigned short)xl[k2]);
  }
  if (r < 31 && j+1 < PEG_L){
    short8 xr = *(const short8*)(base + (size_t)(j+2)*512);
    #pragma unroll
    for (int k2=0;k2<8;k2++) acc[k2] += wv2[k2]*b2f((unsigned short)xr[k2]);
  }
  if (r2 > 0){
    int p = jj - 17; if (p < 0) p += PEG_L;
    short8 xl = *(const short8*)(base + (size_t)(p+1)*512);
    #pragma unroll
    for (int k2=0;k2<8;k2++) acc[k2] += wv0[k2]*b2f((unsigned short)xl[k2]);
  }
  if (r2 < 31 && jj+1 < PEG_L){
    int p = jj - 15; if (p < 0) p += PEG_L;
    short8 xr = *(const short8*)(base + (size_t)(p+1)*512);
    #pragma unroll
    for (int k2=0;k2<8;k2++) acc[k2] += wv2[k2]*b2f((unsigned short)xr[k2]);
  }
  unsigned short o[8];
  #pragma unroll
  for (int k2=0;k2<8;k2++) o[k2] = f2b(acc[k2]);
  *(short8*)op = *(short8*)o;
}

// ---------------- V transpose: vp [B][5120][512] -> vpT [B*H][64][5120] ----------------
__global__ __launch_bounds__(256) void k_vtrans(const unsigned short* __restrict__ vp,
                                                unsigned short* __restrict__ vpT){
  __shared__ unsigned short t[64][72];
  const int bh = blockIdx.y, b = bh>>3, h = bh&7;
  const int k0 = blockIdx.x*64;
  const int tid = threadIdx.x;
  #pragma unroll
  for (int it=0; it<2; ++it){
    int idx = tid + it*256;
    int key = idx>>3, dg = idx&7;
    short8 v = *(const short8*)(vp + ((size_t)b*NKEYS + k0+key)*512 + h*64 + dg*8);
    #pragma unroll
    for (int jj=0;jj<8;++jj) t[dg*8+jj][key] = (unsigned short)v[jj];
  }
  __syncthreads();
  #pragma unroll
  for (int it=0; it<2; ++it){
    int idx = tid + it*256;
    int d = idx>>3, kg = idx&7;
    short8 v = *(const short8*)&t[d][kg*8];
    *(short8*)(vpT + ((size_t)bh*64 + d)*NKEYS + k0 + kg*8) = v;
  }
}

// ---------------- Flash attention (key-split, 32-key subtile pipeline) ----------------
// grid (32, 16, NSPLIT); 4 waves x 32 q; per 64-key LDS tile, softmax+pack+PV run per
// 32-key subtile so only one f32x16 score block is live at a time (fits 128 VGPRs).
__global__ __launch_bounds__(256, 4) void k_attn(
    const unsigned short* __restrict__ qb,
    const unsigned short* __restrict__ kp,
    const unsigned short* __restrict__ vpT,
    unsigned short* __restrict__ oP,
    float* __restrict__ ml){
  __shared__ unsigned short Kl[2][64][72];
  __shared__ unsigned short Vl[2][64][72];
  const int tid = threadIdx.x;
  const int w = tid >> 6, lid = tid & 63;
  const int lq = lid & 31, hi = lid >> 5;
  const int bh = blockIdx.y, b = bh >> 3, h = bh & 7;
  const int sp = blockIdx.z;
  const int q = blockIdx.x*128 + w*32 + lq;

  bf16x8 qreg[4];
  {
    const unsigned short* qr = qb + (size_t)(b*SEQ_N + q)*512 + h*64 + hi*8;
    #pragma unroll
    for (int dt=0; dt<4; ++dt) qreg[dt] = *(const bf16x8*)(qr + dt*16);
  }

  f32x16 o0 = {}, o1 = {};
  float mraw = -3.0e38f, lsum = 0.f;   // lsum = this half's partial

  const int srow = tid >> 2, sg = tid & 3;
  const unsigned short* kst = kp + (size_t)b*NKEYS*512 + h*64
                              + (size_t)(sp*KEYS_PER_SPLIT)*512 + (size_t)srow*512 + sg*8;
  const unsigned short* vst = vpT + (size_t)bh*64*NKEYS + (size_t)srow*NKEYS
                              + sp*KEYS_PER_SPLIT + sg*8;

  {
    short8 a0 = *(const short8*)(kst);
    short8 a1 = *(const short8*)(kst + 32);
    short8 v0 = *(const short8*)(vst);
    short8 v1 = *(const short8*)(vst + 32);
    *(short8*)&Kl[0][srow][sg*8]    = a0;
    *(short8*)&Kl[0][srow][32+sg*8] = a1;
    *(short8*)&Vl[0][srow][sg*8]    = v0;
    *(short8*)&Vl[0][srow][32+sg*8] = v1;
  }
  __syncthreads();

  const float c2 = 0.18033688011f;   // 0.125 * log2(e)
  int cur = 0;

  // softmax + pack + PV for one 32-key subtile; sl base 0 (keys 0..31) or 2 (keys 32..63)
  auto process32 = [&](f32x16 s, const int slb){
    f32x8 sl8 = __builtin_shufflevector(s, s, 0,1,2,3,4,5,6,7);
    f32x8 sh8 = __builtin_shufflevector(s, s, 8,9,10,11,12,13,14,15);
    f32x8 m8 = __builtin_elementwise_max(sl8, sh8);
    f32x4 m4 = __builtin_elementwise_max(f32x4{m8[0],m8[1],m8[2],m8[3]},
                                         f32x4{m8[4],m8[5],m8[6],m8[7]});
    float pm = fmaxf(fmaxf(m4[0],m4[1]), fmaxf(m4[2],m4[3]));
    if (!__all(pm <= mraw + 64.0f)){
      float pg = fmaxf(pm, __shfl_xor(pm, 32, 64));
      float mnew = fmaxf(mraw, pg);
      float al = exp2f((mraw - mnew)*c2);
      #pragma unroll
      for (int i=0;i<16;++i){ o0[i]*=al; o1[i]*=al; }
      lsum *= al;
      mraw = mnew;
    }
    const float nmc = -(mraw * c2);
    #pragma unroll
    for (int i=0;i<16;++i) s[i] = exp2f(fmaf(s[i], c2, nmc));
    {
      f32x8 pa = __builtin_shufflevector(s, s, 0,1,2,3,4,5,6,7);
      f32x8 pb8 = __builtin_shufflevector(s, s, 8,9,10,11,12,13,14,15);
      f32x8 u = pa + pb8;
      f32x4 u4 = f32x4{u[0],u[1],u[2],u[3]} + f32x4{u[4],u[5],u[6],u[7]};
      lsum += (u4[0]+u4[1]) + (u4[2]+u4[3]);
    }
    #pragma unroll
    for (int k2=0; k2<2; ++k2){
      const int sl = slb + k2;
      const int rb = k2*8;
      unsigned w0 = cvtpk(s[rb+0], s[rb+1]);
      unsigned w1 = cvtpk(s[rb+2], s[rb+3]);
      unsigned w2 = cvtpk(s[rb+4], s[rb+5]);
      unsigned w3 = cvtpk(s[rb+6], s[rb+7]);
      unsigned u0 = hi ? w0 : w2;
      unsigned u1 = hi ? w1 : w3;
      unsigned su0 = __shfl_xor(u0, 32, 64);
      unsigned su1 = __shfl_xor(u1, 32, 64);
      unsigned e0 = hi ? su0 : w0;
      unsigned e1 = hi ? su1 : w1;
      unsigned e2 = hi ? w2 : su0;
      unsigned e3 = hi ? w3 : su1;
      uint4v wv = {e0, e1, e2, e3};
      bf16x8 pb = __builtin_bit_cast(bf16x8, wv);
      bf16x8 vf0 = *(const bf16x8*)&Vl[cur][lq][sl*16 + hi*8];
      bf16x8 vf1 = *(const bf16x8*)&Vl[cur][32+lq][sl*16 + hi*8];
      __builtin_amdgcn_s_setprio(1);
      o0 = __builtin_amdgcn_mfma_f32_32x32x16_bf16(vf0, pb, o0, 0,0,0);
      o1 = __builtin_amdgcn_mfma_f32_32x32x16_bf16(vf1, pb, o1, 0,0,0);
      __builtin_amdgcn_s_setprio(0);
    }
  };

  for (int kt=0; kt<NT_SPLIT; ++kt){
    short8 a0, a1, v0s, v1s;
    const bool pf = (kt+1) < NT_SPLIT;
    if (pf){
      const unsigned short* kn = kst + (size_t)(kt+1)*64*512;
      const unsigned short* vn = vst + (size_t)(kt+1)*64;
      a0  = *(const short8*)(kn);
      a1  = *(const short8*)(kn + 32);
      v0s = *(const short8*)(vn);
      v1s = *(const short8*)(vn + 32);
    }

    {
      f32x16 s = {};
      __builtin_amdgcn_s_setprio(1);
      #pragma unroll
      for (int dt=0; dt<4; ++dt){
        bf16x8 kf0 = *(const bf16x8*)&Kl[cur][lq][dt*16 + hi*8];
        s = __builtin_amdgcn_mfma_f32_32x32x16_bf16(kf0, qreg[dt], s, 0,0,0);
      }
      __builtin_amdgcn_s_setprio(0);
      process32(s, 0);
    }
    {
      f32x16 s = {};
      __builtin_amdgcn_s_setprio(1);
      #pragma unroll
      for (int dt=0; dt<4; ++dt){
        bf16x8 kf1 = *(const bf16x8*)&Kl[cur][32+lq][dt*16 + hi*8];
        s = __builtin_amdgcn_mfma_f32_32x32x16_bf16(kf1, qreg[dt], s, 0,0,0);
      }
      __builtin_amdgcn_s_setprio(0);
      process32(s, 2);
    }

    if (pf){
      *(short8*)&Kl[cur^1][srow][sg*8]    = a0;
      *(short8*)&Kl[cur^1][srow][32+sg*8] = a1;
      *(short8*)&Vl[cur^1][srow][sg*8]    = v0s;
      *(short8*)&Vl[cur^1][srow][32+sg*8] = v1s;
    }
    __syncthreads();
    cur ^= 1;
  }

  const float lt = lsum + __shfl_xor(lsum, 32, 64);
  const float inv = 1.0f / lt;
  unsigned short* op = oP + (((size_t)(sp*16 + bh)*SEQ_N + q)*64);
  #pragma unroll
  for (int r=0; r<16; r+=2){
    const int dloc = (r&3) + 8*(r>>2) + 4*hi;
    *(unsigned*)(op + dloc)      = cvtpk(o0[r]*inv, o0[r+1]*inv);
    *(unsigned*)(op + 32 + dloc) = cvtpk(o1[r]*inv, o1[r+1]*inv);
  }
  float* mlp = ml + ((size_t)(sp*16 + bh)*SEQ_N + q)*2;
  mlp[0] = mraw;
  mlp[1] = lt;
}

// ---------------- combine two key-splits ----------------
__global__ __launch_bounds__(256) void k_combine(const unsigned short* __restrict__ oP,
    const float* __restrict__ ml, unsigned short* __restrict__ attnb){
  const float c2 = 0.18033688011f;
  int idx = blockIdx.x*256 + threadIdx.x;     // 4096*16*8 threads
  int dg = idx & 7;
  int qbh = idx >> 3;
  int q = qbh & 4095;
  int bh = qbh >> 12;
  int b = bh >> 3, h = bh & 7;
  size_t i0 = ((size_t)bh*SEQ_N + q);
  size_t i1 = ((size_t)(16 + bh)*SEQ_N + q);
  short8 a = *(const short8*)(oP + i0*64 + dg*8);
  short8 c = *(const short8*)(oP + i1*64 + dg*8);
  float m0 = ml[i0*2], l0 = ml[i0*2+1];
  float m1 = ml[i1*2], l1 = ml[i1*2+1];
  float ms = fmaxf(m0, m1);
  float w0 = l0 * exp2f((m0 - ms)*c2);
  float w1 = l1 * exp2f((m1 - ms)*c2);
  float inv = 1.0f / (w0 + w1);
  float a0 = w0*inv, a1 = w1*inv;
  unsigned short o[8];
  #pragma unroll
  for (int k2=0;k2<8;k2++)
    o[k2] = f2b(a0*b2f((unsigned short)a[k2]) + a1*b2f((unsigned short)c[k2]));
  *(short8*)(attnb + ((size_t)(b*SEQ_N + q)*512) + h*64 + dg*8) = *(short8*)o;
}

extern "C" void kernel_launch(void* const* d_in, const int* in_sizes, int n_in,
                              void* d_out, int out_size, void* d_ws, size_t ws_size,
                              hipStream_t stream){
  const float* x     = (const float*)d_in[0];
  const float* mem   = (const float*)d_in[1];
  const float* ln_g  = (const float*)d_in[2];
  const float* ln_b  = (const float*)d_in[3];
  const float* w_qkv = (const float*)d_in[4];
  const float* w_out = (const float*)d_in[5];
  const float* b_out = (const float*)d_in[6];
  const float* pk_w  = (const float*)d_in[7];
  const float* pk_b  = (const float*)d_in[8];
  const float* pv_w  = (const float*)d_in[9];
  const float* pv_b  = (const float*)d_in[10];
  float* outp = (float*)d_out;

  char* ws = (char*)d_ws;
  size_t off = 0;
  auto alloc = [&](size_t bytes)->void*{
    void* p = ws + off; off += (bytes + 255) & ~(size_t)255; return p;
  };
  unsigned short* wqkvT = (unsigned short*)alloc((size_t)1536*512*2);
  unsigned short* woutT = (unsigned short*)alloc((size_t)512*512*2);
  unsigned short* xn    = (unsigned short*)alloc((size_t)8192*512*2);
  unsigned short* q_b   = (unsigned short*)alloc((size_t)8192*512*2);
  unsigned short* kf    = (unsigned short*)alloc((size_t)2*NKEYS*512*2);
  unsigned short* vf    = (unsigned short*)alloc((size_t)2*NKEYS*512*2);
  unsigned short* kpg   = (unsigned short*)alloc((size_t)2*NKEYS*512*2);
  unsigned short* vpg   = (unsigned short*)alloc((size_t)2*NKEYS*512*2);
  unsigned short* vpT   = (unsigned short*)alloc((size_t)2*NKEYS*512*2);
  unsigned short* attnb = (unsigned short*)alloc((size_t)8192*512*2);

  // Split-attention partials overlay the dead kf/vf region (kf,vf are adjacent):
  // oP: 2 splits x 16 bh x 4096 q x 64 d bf16 = 16.78 MB; ml: 2x16x4096x2 f32 = 1.05 MB.
  unsigned short* oP = kf;
  float* ml = (float*)((char*)kf + (size_t)NSPLIT*16*SEQ_N*64*2);

  k_transpose_w<<<dim3(48,16), dim3(32,8), 0, stream>>>(w_qkv, wqkvT, 512, 1536);
  k_transpose_w<<<dim3(16,16), dim3(32,8), 0, stream>>>(w_out, woutT, 512, 512);
  k_layernorm<<<2048, 256, 0, stream>>>(x, ln_g, ln_b, xn);
  k_memcat<<<512, 256, 0, stream>>>(mem, kf, vf);
  k_gemm<0><<<dim3(128,24), 256, 0, stream>>>(xn, wqkvT, nullptr, q_b, kf, vf, nullptr);
  k_peg<<<2560, 256, 0, stream>>>(kf, pk_w, pk_b, kpg);
  k_peg<<<2560, 256, 0, stream>>>(vf, pv_w, pv_b, vpg);
  k_vtrans<<<dim3(80,16), 256, 0, stream>>>(vpg, vpT);
  k_attn<<<dim3(32,16,NSPLIT), 256, 0, stream>>>(q_b, kpg, vpT, oP, ml);
  k_combine<<<2048, 256, 0, stream>>>(oP, ml, attnb);
  k_gemm<1><<<dim3(128,8), 256, 0, stream>>>(attnb, woutT, b_out, nullptr, nullptr, nullptr, outp);
}

// Round 7
// 282.338 us; speedup vs baseline: 1.6005x; 1.1019x over previous
//
#include <hip/hip_runtime.h>
#include <hip/hip_bf16.h>

typedef short short8 __attribute__((ext_vector_type(8)));
typedef __bf16 bf16x8 __attribute__((ext_vector_type(8)));
typedef float f32x4 __attribute__((ext_vector_type(4)));
typedef float f32x8 __attribute__((ext_vector_type(8)));
typedef float f32x16 __attribute__((ext_vector_type(16)));
typedef unsigned int uint4v __attribute__((ext_vector_type(4)));

#define SEQ_N 4096
#define NKEYS 5120
#define PEG_L 5119
#define NSPLIT 2
#define KEYS_PER_SPLIT 2560
#define NT_SPLIT 40

__device__ __forceinline__ float b2f(unsigned short s){
  union{unsigned u; float f;} v; v.u = ((unsigned)s)<<16; return v.f;
}
__device__ __forceinline__ unsigned short f2b(float f){
  unsigned u = __builtin_bit_cast(unsigned, f);
  u += 0x7fffu + ((u>>16)&1u);
  return (unsigned short)(u>>16);
}
__device__ __forceinline__ unsigned cvtpk(float lo, float hi){
  unsigned r;
  asm("v_cvt_pk_bf16_f32 %0, %1, %2" : "=v"(r) : "v"(lo), "v"(hi));
  return r;
}

// ---------------- weight transpose f32 -> bf16 ----------------
__global__ void k_transpose_w(const float* __restrict__ src, unsigned short* __restrict__ dst,
                              int K, int Ncols){
  __shared__ float t[32][33];
  int tx = threadIdx.x, ty = threadIdx.y;
  int bx = blockIdx.x, by = blockIdx.y;
  #pragma unroll
  for (int i=0;i<4;i++){
    int r = by*32 + ty + 8*i, c = bx*32 + tx;
    t[ty+8*i][tx] = src[(size_t)r*Ncols + c];
  }
  __syncthreads();
  #pragma unroll
  for (int i=0;i<4;i++){
    int r = bx*32 + ty + 8*i, c = by*32 + tx;
    dst[(size_t)r*K + c] = f2b(t[tx][ty+8*i]);
  }
}

// ---------------- LayerNorm: x f32 [8192][512] -> xn bf16 ----------------
__global__ __launch_bounds__(256) void k_layernorm(const float* __restrict__ x,
    const float* __restrict__ g, const float* __restrict__ bb,
    unsigned short* __restrict__ xn){
  int w = threadIdx.x >> 6, l = threadIdx.x & 63;
  int row = blockIdx.x*4 + w;
  const float* xr = x + (size_t)row*512 + l*8;
  f32x4 a = *(const f32x4*)xr;
  f32x4 c4 = *(const f32x4*)(xr+4);
  float s = a[0]+a[1]+a[2]+a[3]+c4[0]+c4[1]+c4[2]+c4[3];
  #pragma unroll
  for (int d=1; d<64; d<<=1) s += __shfl_xor(s, d);
  float mu = s * (1.0f/512.0f);
  float vs = 0.f;
  #pragma unroll
  for (int i=0;i<4;i++){ float d0=a[i]-mu; vs += d0*d0; }
  #pragma unroll
  for (int i=0;i<4;i++){ float d0=c4[i]-mu; vs += d0*d0; }
  #pragma unroll
  for (int d=1; d<64; d<<=1) vs += __shfl_xor(vs, d);
  float rstd = rsqrtf(vs*(1.0f/512.0f) + 1e-5f);
  const float* gp = g + l*8;
  const float* bp = bb + l*8;
  unsigned short o[8];
  #pragma unroll
  for (int i=0;i<8;i++){
    float xi = (i<4)? a[i] : c4[i-4];
    o[i] = f2b((xi-mu)*rstd*gp[i] + bp[i]);
  }
  *(short8*)(xn + (size_t)row*512 + l*8) = *(short8*)o;
}

// ---------------- mem f32 -> bf16 into kf/vf rows 4096..5119 ----------------
__global__ void k_memcat(const float* __restrict__ mem,
                         unsigned short* __restrict__ kf, unsigned short* __restrict__ vf){
  size_t e0 = ((size_t)blockIdx.x*256 + threadIdx.x)*8;
  f32x4 a = *(const f32x4*)(mem+e0);
  f32x4 c4 = *(const f32x4*)(mem+e0+4);
  unsigned short o[8];
  #pragma unroll
  for (int i=0;i<8;i++) o[i] = f2b((i<4)? a[i] : c4[i-4]);
  int c = (int)(e0 & 511);
  size_t row = e0 >> 9;
  size_t b = row >> 10, r = row & 1023;
  size_t dst = ((b*NKEYS) + 4096 + r)*512 + c;
  *(short8*)(kf+dst) = *(short8*)o;
  *(short8*)(vf+dst) = *(short8*)o;
}

// ---------------- GEMM 128x128 tile, BK=64: C = A[rows][512] * BT[cols][512]^T ----------------
// 4 waves; wave w owns rows [w*32, w*32+32) x 128 cols: acc[2][8] f32x4.
template<int EPI>
__global__ __launch_bounds__(256) void k_gemm2(const unsigned short* __restrict__ A,
    const unsigned short* __restrict__ BT, const float* __restrict__ bias,
    unsigned short* __restrict__ qb, unsigned short* __restrict__ kf,
    unsigned short* __restrict__ vf, float* __restrict__ outf){
  __shared__ unsigned short Al[128][72];
  __shared__ unsigned short Bl[128][72];
  const int tid = threadIdx.x;
  const int w = tid>>6, l = tid&63, m = l&15, hh = l>>4;
  const int m0 = blockIdx.x*128, n0 = blockIdx.y*128;
  f32x4 acc[2][8];
  #pragma unroll
  for (int mt=0; mt<2; ++mt)
    #pragma unroll
    for (int nt=0; nt<8; ++nt) acc[mt][nt] = f32x4{0.f,0.f,0.f,0.f};

  for (int kt=0; kt<8; ++kt){
    short8 av[4], bv[4];
    #pragma unroll
    for (int i=0;i<4;++i){
      int c = tid + i*256;          // 0..1023
      int row = c >> 3, c8 = (c & 7)*8;
      av[i] = *(const short8*)(A  + (size_t)(m0+row)*512 + kt*64 + c8);
      bv[i] = *(const short8*)(BT + (size_t)(n0+row)*512 + kt*64 + c8);
    }
    __syncthreads();
    #pragma unroll
    for (int i=0;i<4;++i){
      int c = tid + i*256;
      int row = c >> 3, c8 = (c & 7)*8;
      *(short8*)&Al[row][c8] = av[i];
      *(short8*)&Bl[row][c8] = bv[i];
    }
    __syncthreads();
    #pragma unroll
    for (int ks=0; ks<2; ++ks){
      bf16x8 af[2];
      #pragma unroll
      for (int mt=0; mt<2; ++mt)
        af[mt] = *(const bf16x8*)&Al[w*32 + mt*16 + m][ks*32 + hh*8];
      #pragma unroll
      for (int nt=0; nt<8; ++nt){
        bf16x8 bfv = *(const bf16x8*)&Bl[nt*16+m][ks*32 + hh*8];
        #pragma unroll
        for (int mt=0; mt<2; ++mt)
          acc[mt][nt] = __builtin_amdgcn_mfma_f32_16x16x32_bf16(af[mt], bfv, acc[mt][nt], 0,0,0);
      }
    }
  }
  #pragma unroll
  for (int mt=0; mt<2; ++mt){
    #pragma unroll
    for (int nt=0; nt<8; ++nt){
      #pragma unroll
      for (int j=0; j<4; ++j){
        int grow = m0 + w*32 + mt*16 + 4*hh + j;
        int gcol = n0 + nt*16 + m;
        float v = acc[mt][nt][j];
        if (EPI==0){
          int b = grow >> 12, n = grow & 4095;
          if (gcol < 512)       qb[(size_t)grow*512 + gcol] = f2b(v);
          else if (gcol < 1024) kf[((size_t)b*NKEYS + n)*512 + (gcol-512)]  = f2b(v);
          else                  vf[((size_t)b*NKEYS + n)*512 + (gcol-1024)] = f2b(v);
        } else {
          outf[(size_t)grow*512 + gcol] = v + bias[gcol];
        }
      }
    }
  }
}

// ---------------- PEG1D on rows 1..5119 ----------------
__global__ __launch_bounds__(256) void k_peg(const unsigned short* __restrict__ in,
    const float* __restrict__ w3, const float* __restrict__ bias,
    unsigned short* __restrict__ out){
  int idx = blockIdx.x*256 + threadIdx.x;
  int cg = idx & 63;
  int i  = (idx >> 6) % NKEYS;
  int b  = (idx >> 6) / NKEYS;
  int c0 = cg*8;
  const unsigned short* base = in + (size_t)b*NKEYS*512 + c0;
  unsigned short* op = out + ((size_t)b*NKEYS + i)*512 + c0;
  if (i == 0){ *(short8*)op = *(const short8*)base; return; }
  int j = i - 1;
  float wv0[8], wv1[8], wv2[8], bv[8], acc[8];
  #pragma unroll
  for (int k2=0;k2<8;k2++){
    wv0[k2] = w3[(c0+k2)*3 + 0];
    wv1[k2] = w3[(c0+k2)*3 + 1];
    wv2[k2] = w3[(c0+k2)*3 + 2];
    bv[k2]  = bias[c0+k2];
  }
  short8 xc = *(const short8*)(base + (size_t)i*512);
  #pragma unroll
  for (int k2=0;k2<8;k2++)
    acc[k2] = b2f((unsigned short)xc[k2]) * (1.0f + 2.0f*wv1[k2]) + 2.0f*bv[k2];
  int r = j & 31;
  int jj = j + 16; if (jj >= PEG_L) jj -= PEG_L;
  int r2 = jj & 31;
  if (r > 0){
    short8 xl = *(const short8*)(base + (size_t)j*512);
    #pragma unroll
    for (int k2=0;k2<8;k2++) acc[k2] += wv0[k2]*b2f((unsigned short)xl[k2]);
  }
  if (r < 31 && j+1 < PEG_L){
    short8 xr = *(const short8*)(base + (size_t)(j+2)*512);
    #pragma unroll
    for (int k2=0;k2<8;k2++) acc[k2] += wv2[k2]*b2f((unsigned short)xr[k2]);
  }
  if (r2 > 0){
    int p = jj - 17; if (p < 0) p += PEG_L;
    short8 xl = *(const short8*)(base + (size_t)(p+1)*512);
    #pragma unroll
    for (int k2=0;k2<8;k2++) acc[k2] += wv0[k2]*b2f((unsigned short)xl[k2]);
  }
  if (r2 < 31 && jj+1 < PEG_L){
    int p = jj - 15; if (p < 0) p += PEG_L;
    short8 xr = *(const short8*)(base + (size_t)(p+1)*512);
    #pragma unroll
    for (int k2=0;k2<8;k2++) acc[k2] += wv2[k2]*b2f((unsigned short)xr[k2]);
  }
  unsigned short o[8];
  #pragma unroll
  for (int k2=0;k2<8;k2++) o[k2] = f2b(acc[k2]);
  *(short8*)op = *(short8*)o;
}

// ---------------- V transpose: vp [B][5120][512] -> vpT [B*H][64][5120] ----------------
__global__ __launch_bounds__(256) void k_vtrans(const unsigned short* __restrict__ vp,
                                                unsigned short* __restrict__ vpT){
  __shared__ unsigned short t[64][72];
  const int bh = blockIdx.y, b = bh>>3, h = bh&7;
  const int k0 = blockIdx.x*64;
  const int tid = threadIdx.x;
  #pragma unroll
  for (int it=0; it<2; ++it){
    int idx = tid + it*256;
    int key = idx>>3, dg = idx&7;
    short8 v = *(const short8*)(vp + ((size_t)b*NKEYS + k0+key)*512 + h*64 + dg*8);
    #pragma unroll
    for (int jj=0;jj<8;++jj) t[dg*8+jj][key] = (unsigned short)v[jj];
  }
  __syncthreads();
  #pragma unroll
  for (int it=0; it<2; ++it){
    int idx = tid + it*256;
    int d = idx>>3, kg = idx&7;
    short8 v = *(const short8*)&t[d][kg*8];
    *(short8*)(vpT + ((size_t)bh*64 + d)*NKEYS + k0 + kg*8) = v;
  }
}

// ---------------- Flash attention (key-split): swapped QK^T, 32x32, in-reg softmax ----------------
// grid (32, 16, NSPLIT); 4 waves x 32 q; raw v_exp_f32; vector lsum accumulator.
__global__ __launch_bounds__(256, 4) void k_attn(
    const unsigned short* __restrict__ qb,
    const unsigned short* __restrict__ kp,
    const unsigned short* __restrict__ vpT,
    unsigned short* __restrict__ oP,
    float* __restrict__ ml){
  __shared__ unsigned short Kl[2][64][72];
  __shared__ unsigned short Vl[2][64][72];
  const int tid = threadIdx.x;
  const int w = tid >> 6, lid = tid & 63;
  const int lq = lid & 31, hi = lid >> 5;
  const int bh = blockIdx.y, b = bh >> 3, h = bh & 7;
  const int sp = blockIdx.z;
  const int q = blockIdx.x*128 + w*32 + lq;

  bf16x8 qreg[4];
  {
    const unsigned short* qr = qb + (size_t)(b*SEQ_N + q)*512 + h*64 + hi*8;
    #pragma unroll
    for (int dt=0; dt<4; ++dt) qreg[dt] = *(const bf16x8*)(qr + dt*16);
  }

  f32x16 o0 = {}, o1 = {};
  f32x8 lsum8 = {};
  float mraw = -3.0e38f;

  const int srow = tid >> 2, sg = tid & 3;
  const unsigned short* kst = kp + (size_t)b*NKEYS*512 + h*64
                              + (size_t)(sp*KEYS_PER_SPLIT)*512 + (size_t)srow*512 + sg*8;
  const unsigned short* vst = vpT + (size_t)bh*64*NKEYS + (size_t)srow*NKEYS
                              + sp*KEYS_PER_SPLIT + sg*8;

  {
    short8 a0 = *(const short8*)(kst);
    short8 a1 = *(const short8*)(kst + 32);
    short8 v0 = *(const short8*)(vst);
    short8 v1 = *(const short8*)(vst + 32);
    *(short8*)&Kl[0][srow][sg*8]    = a0;
    *(short8*)&Kl[0][srow][32+sg*8] = a1;
    *(short8*)&Vl[0][srow][sg*8]    = v0;
    *(short8*)&Vl[0][srow][32+sg*8] = v1;
  }
  __syncthreads();

  const float c2 = 0.18033688011f;   // 0.125 * log2(e)
  int cur = 0;
  for (int kt=0; kt<NT_SPLIT; ++kt){
    short8 a0, a1, v0s, v1s;
    const bool pf = (kt+1) < NT_SPLIT;
    if (pf){
      const unsigned short* kn = kst + (size_t)(kt+1)*64*512;
      const unsigned short* vn = vst + (size_t)(kt+1)*64;
      a0  = *(const short8*)(kn);
      a1  = *(const short8*)(kn + 32);
      v0s = *(const short8*)(vn);
      v1s = *(const short8*)(vn + 32);
    }

    f32x16 s0 = {}, s1 = {};
    #pragma unroll
    for (int dt=0; dt<4; ++dt){
      bf16x8 kf0 = *(const bf16x8*)&Kl[cur][lq][dt*16 + hi*8];
      s0 = __builtin_amdgcn_mfma_f32_32x32x16_bf16(kf0, qreg[dt], s0, 0,0,0);
    }
    #pragma unroll
    for (int dt=0; dt<4; ++dt){
      bf16x8 kf1 = *(const bf16x8*)&Kl[cur][32+lq][dt*16 + hi*8];
      s1 = __builtin_amdgcn_mfma_f32_32x32x16_bf16(kf1, qreg[dt], s1, 0,0,0);
    }

    // local (this half's) max via packed tree
    f32x8 sa0 = __builtin_shufflevector(s0, s0, 0,1,2,3,4,5,6,7);
    f32x8 sb0 = __builtin_shufflevector(s0, s0, 8,9,10,11,12,13,14,15);
    f32x8 sa1 = __builtin_shufflevector(s1, s1, 0,1,2,3,4,5,6,7);
    f32x8 sb1 = __builtin_shufflevector(s1, s1, 8,9,10,11,12,13,14,15);
    f32x8 mx8 = __builtin_elementwise_max(__builtin_elementwise_max(sa0, sb0),
                                          __builtin_elementwise_max(sa1, sb1));
    float pm = fmaxf(fmaxf(fmaxf(mx8[0],mx8[1]), fmaxf(mx8[2],mx8[3])),
                     fmaxf(fmaxf(mx8[4],mx8[5]), fmaxf(mx8[6],mx8[7])));

    // defer-max: cross-half exchange + rescale only when some lane exceeds slack
    if (!__all(pm <= mraw + 64.0f)){
      float pg = fmaxf(pm, __shfl_xor(pm, 32, 64));
      float mnew = fmaxf(mraw, pg);
      float al = __builtin_amdgcn_exp2f((mraw - mnew)*c2);
      #pragma unroll
      for (int i=0;i<16;++i){ o0[i]*=al; o1[i]*=al; }
      #pragma unroll
      for (int i=0;i<8;++i) lsum8[i] *= al;
      mraw = mnew;
    }
    const float nmc = -(mraw * c2);
    #pragma unroll
    for (int i=0;i<16;++i){
      s0[i] = __builtin_amdgcn_exp2f(fmaf(s0[i], c2, nmc));
      s1[i] = __builtin_amdgcn_exp2f(fmaf(s1[i], c2, nmc));
    }
    // vector partial sum (horizontal reduce deferred to epilogue)
    {
      f32x8 pa0 = __builtin_shufflevector(s0, s0, 0,1,2,3,4,5,6,7);
      f32x8 pb0 = __builtin_shufflevector(s0, s0, 8,9,10,11,12,13,14,15);
      f32x8 pa1 = __builtin_shufflevector(s1, s1, 0,1,2,3,4,5,6,7);
      f32x8 pb1 = __builtin_shufflevector(s1, s1, 8,9,10,11,12,13,14,15);
      lsum8 += (pa0 + pb0) + (pa1 + pb1);
    }

    // P -> bf16 B-fragments (HW cvt_pk), one cross-half exchange per 16-key slice
    #pragma unroll
    for (int sl=0; sl<4; ++sl){
      const f32x16& sv = (sl < 2) ? s0 : s1;
      const int rb = (sl & 1)*8;
      unsigned w0 = cvtpk(sv[rb+0], sv[rb+1]);
      unsigned w1 = cvtpk(sv[rb+2], sv[rb+3]);
      unsigned w2 = cvtpk(sv[rb+4], sv[rb+5]);
      unsigned w3 = cvtpk(sv[rb+6], sv[rb+7]);
      unsigned u0 = hi ? w0 : w2;
      unsigned u1 = hi ? w1 : w3;
      unsigned su0 = __shfl_xor(u0, 32, 64);
      unsigned su1 = __shfl_xor(u1, 32, 64);
      unsigned e0 = hi ? su0 : w0;
      unsigned e1 = hi ? su1 : w1;
      unsigned e2 = hi ? w2 : su0;
      unsigned e3 = hi ? w3 : su1;
      uint4v wv = {e0, e1, e2, e3};
      bf16x8 pb = __builtin_bit_cast(bf16x8, wv);
      bf16x8 vf0 = *(const bf16x8*)&Vl[cur][lq][sl*16 + hi*8];
      o0 = __builtin_amdgcn_mfma_f32_32x32x16_bf16(vf0, pb, o0, 0,0,0);
      bf16x8 vf1 = *(const bf16x8*)&Vl[cur][32+lq][sl*16 + hi*8];
      o1 = __builtin_amdgcn_mfma_f32_32x32x16_bf16(vf1, pb, o1, 0,0,0);
    }

    if (pf){
      *(short8*)&Kl[cur^1][srow][sg*8]    = a0;
      *(short8*)&Kl[cur^1][srow][32+sg*8] = a1;
      *(short8*)&Vl[cur^1][srow][sg*8]    = v0s;
      *(short8*)&Vl[cur^1][srow][32+sg*8] = v1s;
    }
    __syncthreads();
    cur ^= 1;
  }

  f32x4 l4 = f32x4{lsum8[0],lsum8[1],lsum8[2],lsum8[3]} + f32x4{lsum8[4],lsum8[5],lsum8[6],lsum8[7]};
  float lsum = (l4[0]+l4[1]) + (l4[2]+l4[3]);
  const float lt = lsum + __shfl_xor(lsum, 32, 64);
  const float inv = __builtin_amdgcn_rcpf(lt);
  unsigned short* op = oP + (((size_t)(sp*16 + bh)*SEQ_N + q)*64);
  #pragma unroll
  for (int r=0; r<16; r+=2){
    const int dloc = (r&3) + 8*(r>>2) + 4*hi;
    *(unsigned*)(op + dloc)      = cvtpk(o0[r]*inv, o0[r+1]*inv);
    *(unsigned*)(op + 32 + dloc) = cvtpk(o1[r]*inv, o1[r+1]*inv);
  }
  float* mlp = ml + ((size_t)(sp*16 + bh)*SEQ_N + q)*2;
  mlp[0] = mraw;
  mlp[1] = lt;
}

// ---------------- combine two key-splits ----------------
__global__ __launch_bounds__(256) void k_combine(const unsigned short* __restrict__ oP,
    const float* __restrict__ ml, unsigned short* __restrict__ attnb){
  const float c2 = 0.18033688011f;
  int idx = blockIdx.x*256 + threadIdx.x;     // 4096*16*8 threads
  int dg = idx & 7;
  int qbh = idx >> 3;
  int q = qbh & 4095;
  int bh = qbh >> 12;
  int b = bh >> 3, h = bh & 7;
  size_t i0 = ((size_t)bh*SEQ_N + q);
  size_t i1 = ((size_t)(16 + bh)*SEQ_N + q);
  short8 a = *(const short8*)(oP + i0*64 + dg*8);
  short8 c = *(const short8*)(oP + i1*64 + dg*8);
  float m0 = ml[i0*2], l0 = ml[i0*2+1];
  float m1 = ml[i1*2], l1 = ml[i1*2+1];
  float ms = fmaxf(m0, m1);
  float w0 = l0 * __builtin_amdgcn_exp2f((m0 - ms)*c2);
  float w1 = l1 * __builtin_amdgcn_exp2f((m1 - ms)*c2);
  float inv = 1.0f / (w0 + w1);
  float a0 = w0*inv, a1 = w1*inv;
  unsigned short o[8];
  #pragma unroll
  for (int k2=0;k2<8;k2++)
    o[k2] = f2b(a0*b2f((unsigned short)a[k2]) + a1*b2f((unsigned short)c[k2]));
  *(short8*)(attnb + ((size_t)(b*SEQ_N + q)*512) + h*64 + dg*8) = *(short8*)o;
}

extern "C" void kernel_launch(void* const* d_in, const int* in_sizes, int n_in,
                              void* d_out, int out_size, void* d_ws, size_t ws_size,
                              hipStream_t stream){
  const float* x     = (const float*)d_in[0];
  const float* mem   = (const float*)d_in[1];
  const float* ln_g  = (const float*)d_in[2];
  const float* ln_b  = (const float*)d_in[3];
  const float* w_qkv = (const float*)d_in[4];
  const float* w_out = (const float*)d_in[5];
  const float* b_out = (const float*)d_in[6];
  const float* pk_w  = (const float*)d_in[7];
  const float* pk_b  = (const float*)d_in[8];
  const float* pv_w  = (const float*)d_in[9];
  const float* pv_b  = (const float*)d_in[10];
  float* outp = (float*)d_out;

  char* ws = (char*)d_ws;
  size_t off = 0;
  auto alloc = [&](size_t bytes)->void*{
    void* p = ws + off; off += (bytes + 255) & ~(size_t)255; return p;
  };
  unsigned short* wqkvT = (unsigned short*)alloc((size_t)1536*512*2);
  unsigned short* woutT = (unsigned short*)alloc((size_t)512*512*2);
  unsigned short* xn    = (unsigned short*)alloc((size_t)8192*512*2);
  unsigned short* q_b   = (unsigned short*)alloc((size_t)8192*512*2);
  unsigned short* kf    = (unsigned short*)alloc((size_t)2*NKEYS*512*2);
  unsigned short* vf    = (unsigned short*)alloc((size_t)2*NKEYS*512*2);
  unsigned short* kpg   = (unsigned short*)alloc((size_t)2*NKEYS*512*2);
  unsigned short* vpg   = (unsigned short*)alloc((size_t)2*NKEYS*512*2);
  unsigned short* vpT   = (unsigned short*)alloc((size_t)2*NKEYS*512*2);
  unsigned short* attnb = (unsigned short*)alloc((size_t)8192*512*2);

  // Split-attention partials overlay the dead kf/vf region (kf,vf are adjacent):
  unsigned short* oP = kf;
  float* ml = (float*)((char*)kf + (size_t)NSPLIT*16*SEQ_N*64*2);

  k_transpose_w<<<dim3(48,16), dim3(32,8), 0, stream>>>(w_qkv, wqkvT, 512, 1536);
  k_transpose_w<<<dim3(16,16), dim3(32,8), 0, stream>>>(w_out, woutT, 512, 512);
  k_layernorm<<<2048, 256, 0, stream>>>(x, ln_g, ln_b, xn);
  k_memcat<<<512, 256, 0, stream>>>(mem, kf, vf);
  k_gemm2<0><<<dim3(64,12), 256, 0, stream>>>(xn, wqkvT, nullptr, q_b, kf, vf, nullptr);
  k_peg<<<2560, 256, 0, stream>>>(kf, pk_w, pk_b, kpg);
  k_peg<<<2560, 256, 0, stream>>>(vf, pv_w, pv_b, vpg);
  k_vtrans<<<dim3(80,16), 256, 0, stream>>>(vpg, vpT);
  k_attn<<<dim3(32,16,NSPLIT), 256, 0, stream>>>(q_b, kpg, vpT, oP, ml);
  k_combine<<<2048, 256, 0, stream>>>(oP, ml, attnb);
  k_gemm2<1><<<dim3(64,4), 256, 0, stream>>>(attnb, woutT, b_out, nullptr, nullptr, nullptr, outp);
}